// Round 12
// baseline (589.813 us; speedup 1.0000x reference)
//
#include <hip/hip_runtime.h>
#include <math.h>

#define BATCH 8
#define PTS   2048
#define NPTS  (BATCH * PTS)
#define KNN   20

typedef short short4v __attribute__((ext_vector_type(4)));
typedef short short8v __attribute__((ext_vector_type(8)));
typedef _Float16 half8v __attribute__((ext_vector_type(8)));
typedef float f32x4 __attribute__((ext_vector_type(4)));

__device__ __forceinline__ short f2h(float f) {
    _Float16 h = (_Float16)f;
    return __builtin_bit_cast(short, h);
}
__device__ __forceinline__ float h2f(_Float16 h) { return (float)h; }

// ---------------------------------------------------------------- build x0 (compact, stride 6)
__global__ void build_x0_kernel(const float* __restrict__ feats,
                                const float* __restrict__ pos,
                                float* __restrict__ x0) {
    int i = blockIdx.x * 256 + threadIdx.x;
    if (i >= NPTS) return;
    float* o = x0 + (size_t)i * 6;
    const float* f = feats + (size_t)i * 3;
    const float* p = pos + (size_t)i * 3;
    o[0] = f[0]; o[1] = f[1]; o[2] = f[2];
    o[3] = p[0]; o[4] = p[1]; o[5] = p[2];
}

// ---------------------------------------------------------------- row norms
template <int D>
__global__ void norm2_kernel(const float* __restrict__ x, float* __restrict__ xn) {
    int i = blockIdx.x * 256 + threadIdx.x;
    if (i >= NPTS) return;
    const float* r = x + (size_t)i * D;
    float s = 0.f;
#pragma unroll
    for (int j = 0; j < D; ++j) s += r[j] * r[j];
    xn[i] = s;
}

// ---------------------------------------------------------------- hi/lo fp16 split (4 elems/thread)
__global__ void split16_kernel(const float* __restrict__ x, unsigned short* __restrict__ xh,
                               unsigned short* __restrict__ xl) {
    int i = blockIdx.x * 256 + threadIdx.x;   // over NPTS*64/4
    float4 v = ((const float4*)x)[i];
    float vv[4] = {v.x, v.y, v.z, v.w};
    short4v hh, ll;
#pragma unroll
    for (int j = 0; j < 4; ++j) {
        _Float16 hf = (_Float16)vv[j];
        hh[j] = __builtin_bit_cast(short, hf);
        _Float16 lf = (_Float16)(vv[j] - (float)hf);
        ll[j] = __builtin_bit_cast(short, lf);
    }
    ((short4v*)xh)[i] = hh;
    ((short4v*)xl)[i] = ll;
}

// ---------------------------------------------------------------- pairwise d2, fp32 VALU (D=6 layer)
template <int D>
__global__ void __launch_bounds__(256) dist_kernel(const float* __restrict__ x,
                                                   const float* __restrict__ xn,
                                                   float* __restrict__ d2, int b0) {
    int bz = blockIdx.z;
    int b  = b0 + bz;
    const float* xb  = x  + (size_t)b * PTS * D;
    const float* xnb = xn + (size_t)b * PTS;
    float* d2b = d2 + (size_t)bz * PTS * PTS;

    __shared__ float As[64][D + 1];
    __shared__ float Bs[64][D + 1];
    int row0 = blockIdx.y * 64;
    int col0 = blockIdx.x * 64;
    int tid = threadIdx.x;
    for (int i = tid; i < 64 * D; i += 256) {
        int r = i / D, c = i - r * D;
        As[r][c] = xb[(size_t)(row0 + r) * D + c];
        Bs[r][c] = xb[(size_t)(col0 + r) * D + c];
    }
    __syncthreads();
    int tx = tid & 15, ty = tid >> 4;
    float acc[4][4] = {};
    for (int k = 0; k < D; ++k) {
        float av[4], bv[4];
#pragma unroll
        for (int i = 0; i < 4; ++i) av[i] = As[ty * 4 + i][k];
#pragma unroll
        for (int j = 0; j < 4; ++j) bv[j] = Bs[tx * 4 + j][k];
#pragma unroll
        for (int i = 0; i < 4; ++i)
#pragma unroll
            for (int j = 0; j < 4; ++j) acc[i][j] += av[i] * bv[j];
    }
#pragma unroll
    for (int i = 0; i < 4; ++i) {
        int r = row0 + ty * 4 + i;
#pragma unroll
        for (int j = 0; j < 4; ++j) {
            int c = col0 + tx * 4 + j;
            d2b[(size_t)r * PTS + c] = xnb[c] - 2.f * acc[i][j];
        }
    }
}

// ---------------------------------------------------------------- pairwise d2 via MFMA hi/lo fp16 (D=64)
__global__ void __launch_bounds__(256) dist_mfma_kernel(
    const unsigned short* __restrict__ xh, const unsigned short* __restrict__ xl,
    const float* __restrict__ xn, float* __restrict__ d2, int b0)
{
    __shared__ char smem[128 * 256 + 64 * 256];   // 48KB: A(32K) | B(16K)
    __shared__ float sxn[64];
    char* sA = smem;
    char* sB = smem + 128 * 256;
    float* sS = (float*)smem;                     // reused after compute
    int bz = blockIdx.z, b = b0 + bz;
    int row0 = blockIdx.y * 128, col0 = blockIdx.x * 64;
    const unsigned short* xhb = xh + (size_t)b * PTS * 64;
    const unsigned short* xlb = xl + (size_t)b * PTS * 64;
    const float* xnb = xn + (size_t)b * PTS;
    float* d2b = d2 + (size_t)bz * PTS * PTS;
    int tid = threadIdx.x;

    for (int i = tid; i < 2048; i += 256) {
        int r = i >> 4, c = i & 15;
        const unsigned short* src = (c < 8) ? xhb + (size_t)(row0 + r) * 64 + (c << 3)
                                            : xlb + (size_t)(row0 + r) * 64 + ((c - 8) << 3);
        *(short8v*)(sA + ((r * 256 + (c << 4)) ^ ((r & 7) << 4))) = *(const short8v*)src;
    }
    for (int i = tid; i < 1024; i += 256) {
        int r = i >> 4, c = i & 15;
        const unsigned short* src = (c < 8) ? xhb + (size_t)(col0 + r) * 64 + (c << 3)
                                            : xlb + (size_t)(col0 + r) * 64 + ((c - 8) << 3);
        *(short8v*)(sB + ((r * 256 + (c << 4)) ^ ((r & 7) << 4))) = *(const short8v*)src;
    }
    if (tid < 64) sxn[tid] = xnb[col0 + tid];
    __syncthreads();

    int w = tid >> 6, l = tid & 63;
    int lr = l & 15, lg = l >> 4;

    half8v bh[4][2], bl[4][2];
#pragma unroll
    for (int n = 0; n < 4; ++n) {
        int c = n * 16 + lr, sw = (c & 7) << 4, base = c * 256;
#pragma unroll
        for (int ks = 0; ks < 2; ++ks) {
            bh[n][ks] = __builtin_bit_cast(half8v, *(short8v*)(sB + ((base + ks * 64 + lg * 16) ^ sw)));
            bl[n][ks] = __builtin_bit_cast(half8v, *(short8v*)(sB + ((base + 128 + ks * 64 + lg * 16) ^ sw)));
        }
    }

    f32x4 acc[2][4];
#pragma unroll
    for (int m = 0; m < 2; ++m)
#pragma unroll
        for (int n = 0; n < 4; ++n) acc[m][n] = (f32x4){0.f, 0.f, 0.f, 0.f};

#pragma unroll
    for (int m = 0; m < 2; ++m) {
        int r = w * 32 + m * 16 + lr, sw = (r & 7) << 4, base = r * 256;
        half8v ah0 = __builtin_bit_cast(half8v, *(short8v*)(sA + ((base + lg * 16) ^ sw)));
        half8v ah1 = __builtin_bit_cast(half8v, *(short8v*)(sA + ((base + 64 + lg * 16) ^ sw)));
        half8v al0 = __builtin_bit_cast(half8v, *(short8v*)(sA + ((base + 128 + lg * 16) ^ sw)));
        half8v al1 = __builtin_bit_cast(half8v, *(short8v*)(sA + ((base + 192 + lg * 16) ^ sw)));
#pragma unroll
        for (int n = 0; n < 4; ++n) {
            f32x4 a = acc[m][n];
            a = __builtin_amdgcn_mfma_f32_16x16x32_f16(ah0, bh[n][0], a, 0, 0, 0);
            a = __builtin_amdgcn_mfma_f32_16x16x32_f16(ah1, bh[n][1], a, 0, 0, 0);
            a = __builtin_amdgcn_mfma_f32_16x16x32_f16(al0, bh[n][0], a, 0, 0, 0);
            a = __builtin_amdgcn_mfma_f32_16x16x32_f16(al1, bh[n][1], a, 0, 0, 0);
            a = __builtin_amdgcn_mfma_f32_16x16x32_f16(ah0, bl[n][0], a, 0, 0, 0);
            a = __builtin_amdgcn_mfma_f32_16x16x32_f16(ah1, bl[n][1], a, 0, 0, 0);
            acc[m][n] = a;
        }
    }
    __syncthreads();   // all sA/sB reads complete; safe to reuse as sS

#pragma unroll
    for (int m = 0; m < 2; ++m)
#pragma unroll
        for (int n = 0; n < 4; ++n) {
            int rl = w * 32 + m * 16 + lg * 4;
            int col = n * 16 + lr;
#pragma unroll
            for (int j = 0; j < 4; ++j)
                sS[(rl + j) * 64 + col] = acc[m][n][j];
        }
    __syncthreads();

    for (int i = tid; i < 2048; i += 256) {
        int r = i >> 4, c4 = (i & 15) << 2;
        float4 v = *(float4*)&sS[r * 64 + c4];
        float4 o;
        o.x = sxn[c4 + 0] - 2.f * v.x;
        o.y = sxn[c4 + 1] - 2.f * v.y;
        o.z = sxn[c4 + 2] - 2.f * v.z;
        o.w = sxn[c4 + 3] - 2.f * v.w;
        *(float4*)&d2b[(size_t)(row0 + r) * PTS + col0 + c4] = o;
    }
}

// ---------------------------------------------------------------- top-K smallest, 1 wave/row, reg-resident
#define GMIN8(B, GV, GJ) do {                                         \
    GV = va[(B)];     GJ = (B);                                       \
    if (va[(B)+1] < GV) { GV = va[(B)+1]; GJ = (B)+1; }               \
    if (va[(B)+2] < GV) { GV = va[(B)+2]; GJ = (B)+2; }               \
    if (va[(B)+3] < GV) { GV = va[(B)+3]; GJ = (B)+3; }               \
    if (va[(B)+4] < GV) { GV = va[(B)+4]; GJ = (B)+4; }               \
    if (va[(B)+5] < GV) { GV = va[(B)+5]; GJ = (B)+5; }               \
    if (va[(B)+6] < GV) { GV = va[(B)+6]; GJ = (B)+6; }               \
    if (va[(B)+7] < GV) { GV = va[(B)+7]; GJ = (B)+7; }               \
} while (0)

#define INVAL8(B, GV, GJ, JS) do {                                    \
    va[(B)+0] = ((B)+0 == (JS)) ? INFV : va[(B)+0];                   \
    va[(B)+1] = ((B)+1 == (JS)) ? INFV : va[(B)+1];                   \
    va[(B)+2] = ((B)+2 == (JS)) ? INFV : va[(B)+2];                   \
    va[(B)+3] = ((B)+3 == (JS)) ? INFV : va[(B)+3];                   \
    va[(B)+4] = ((B)+4 == (JS)) ? INFV : va[(B)+4];                   \
    va[(B)+5] = ((B)+5 == (JS)) ? INFV : va[(B)+5];                   \
    va[(B)+6] = ((B)+6 == (JS)) ? INFV : va[(B)+6];                   \
    va[(B)+7] = ((B)+7 == (JS)) ? INFV : va[(B)+7];                   \
    GMIN8(B, GV, GJ);                                                 \
} while (0)

__global__ void __launch_bounds__(256) topk_kernel(const float* __restrict__ d2,
                                                   int* __restrict__ nbr, int b0) {
    const float INFV = __builtin_inff();
    int wid = threadIdx.x >> 6, lane = threadIdx.x & 63;
    int pl = blockIdx.x * 4 + wid;
    int bz = blockIdx.y;
    const float* row = d2 + ((size_t)bz * PTS + pl) * PTS;

    float va[32];
#pragma unroll
    for (int j8 = 0; j8 < 8; ++j8) {
        float4 v = *(const float4*)&row[j8 * 256 + lane * 4];
        va[j8 * 4 + 0] = v.x; va[j8 * 4 + 1] = v.y;
        va[j8 * 4 + 2] = v.z; va[j8 * 4 + 3] = v.w;
    }

    float g0v, g1v, g2v, g3v;
    int   g0j, g1j, g2j, g3j;
    GMIN8(0,  g0v, g0j);
    GMIN8(8,  g1v, g1j);
    GMIN8(16, g2v, g2j);
    GMIN8(24, g3v, g3j);

    int gbase = (b0 + bz) * PTS;
    int* outp = nbr + (size_t)(gbase + pl) * KNN;

    for (int k = 0; k < KNN; ++k) {
        float lv = g0v; int lj = g0j;
        if (g1v < lv) { lv = g1v; lj = g1j; }
        if (g2v < lv) { lv = g2v; lj = g2j; }
        if (g3v < lv) { lv = g3v; lj = g3j; }
        float wm = lv;
#pragma unroll
        for (int off = 1; off < 64; off <<= 1) wm = fminf(wm, __shfl_xor(wm, off));
        int mycol = (lv == wm) ? (((lj >> 2) << 8) | (lane << 2) | (lj & 3)) : 0x7fffffff;
        int wc = mycol;
#pragma unroll
        for (int off = 1; off < 64; off <<= 1) {
            int oc = __shfl_xor(wc, off);
            wc = oc < wc ? oc : wc;
        }
        if (lane == 0) outp[k] = gbase + wc;
        if (mycol == wc) {
            int js = lj;
            int gs = js >> 3;
            if (gs == 0)      INVAL8(0,  g0v, g0j, js);
            else if (gs == 1) INVAL8(8,  g1v, g1j, js);
            else if (gs == 2) INVAL8(16, g2v, g2j, js);
            else              INVAL8(24, g3v, g3j, js);
        }
    }
}

// ---------------------------------------------------------------- per-layer weight prep
__global__ void prep_kernel(const float* __restrict__ wa, const float* __restrict__ ba,
                            const float* __restrict__ wb,
                            float* __restrict__ wc, float* __restrict__ bc,
                            unsigned short* __restrict__ wbT, int D) {
    int t = blockIdx.x * 256 + threadIdx.x;
    if (t < D * 128) {
        int k = t >> 7, n = t & 127;
        wc[t] = (n < 64) ? (wa[k * 64 + n] - wa[(D + k) * 64 + n])
                         : wa[(D + k) * 64 + (n - 64)];
    }
    if (t < 128) bc[t] = (t < 64) ? ba[t] : 0.f;
    if (t < 4096) {
        int n = t >> 6, k = t & 63;
        wbT[t] = (unsigned short)f2h(wb[k * 64 + n]);
    }
}

// ---------------------------------------------------------------- head weight prep (transposed fp16)
__global__ void prep_head_kernel(const float* __restrict__ hw1, const float* __restrict__ hw2,
                                 const float* __restrict__ hw3,
                                 unsigned short* __restrict__ w1T, unsigned short* __restrict__ w2T,
                                 unsigned short* __restrict__ w3T) {
    int t = blockIdx.x * 256 + threadIdx.x;
    if (t < 192 * 1024) { int k = t / 1024, n = t - k * 1024; w1T[n * 192 + k] = (unsigned short)f2h(hw1[t]); }
    if (t < 1024 * 256) { int k = t >> 8, n = t & 255; w2T[n * 1024 + k] = (unsigned short)f2h(hw2[t]); }
    if (t < 256 * 128)  { int k = t >> 7, n = t & 127; w3T[n * 256 + k] = (unsigned short)f2h(hw3[t]); }
}

// ---------------------------------------------------------------- uv for layer 1 (D=6, compact x0)
__global__ void uv6_kernel(const float* __restrict__ x0, const float* __restrict__ wc,
                           const float* __restrict__ bc, float* __restrict__ uvout) {
    int t = blockIdx.x * 256 + threadIdx.x;
    int i = t >> 7, n = t & 127;
    const float* xr = x0 + (size_t)i * 6;
    float s = bc[n];
#pragma unroll
    for (int r = 0; r < 6; ++r) s += xr[r] * wc[r * 128 + n];
    uvout[t] = s;
}

// ---------------------------------------------------------------- EdgeConv via MFMA (fp16)
__global__ void __launch_bounds__(256) edge_mfma_kernel(
    const float* __restrict__ uv, const int* __restrict__ nbr,
    const unsigned short* __restrict__ wbT, const float* __restrict__ bb,
    float* __restrict__ xout, unsigned short* __restrict__ hcat16, int hoff)
{
    __shared__ short sA[256 * 64];   // 32 KB, swizzled
    __shared__ short sB[64 * 64];    // 8 KB, swizzled (holds wbT)
    __shared__ int snbr[8 * KNN];
    char* cA = (char*)sA;
    char* cB = (char*)sB;
    int tid = threadIdx.x;
    int p0 = blockIdx.x * 8;

    if (tid < 8 * KNN) snbr[tid] = nbr[(size_t)p0 * KNN + tid];
    for (int c = tid; c < 512; c += 256) {
        int n = c >> 3, k0 = (c & 7) << 3;
        short8v w = *(const short8v*)(wbT + n * 64 + k0);
        *(short8v*)(cB + ((n * 128 + (k0 << 1)) ^ ((n & 7) << 4))) = w;
    }
    __syncthreads();

    for (int t = tid; t < 1024; t += 256) {
        int r = t >> 2, c16 = (t & 3) << 4;
        int pl = r >> 5, e = r & 31;
        short h[16] __attribute__((aligned(16)));
        if (e < KNN) {
            int q = snbr[pl * KNN + e];
            const float4* up = (const float4*)(uv + (size_t)(p0 + pl) * 128 + c16);
            const float4* vp = (const float4*)(uv + (size_t)q * 128 + 64 + c16);
#pragma unroll
            for (int j = 0; j < 4; ++j) {
                float4 uu = up[j], vv = vp[j];
                h[j * 4 + 0] = f2h(fmaxf(uu.x + vv.x, 0.f));
                h[j * 4 + 1] = f2h(fmaxf(uu.y + vv.y, 0.f));
                h[j * 4 + 2] = f2h(fmaxf(uu.z + vv.z, 0.f));
                h[j * 4 + 3] = f2h(fmaxf(uu.w + vv.w, 0.f));
            }
        } else {
#pragma unroll
            for (int j = 0; j < 16; ++j) h[j] = 0;
        }
        int base = r * 128 + (c16 << 1);
        int s = (r & 7) << 4;
        *(short8v*)(cA + (base ^ s)) = *(short8v*)(h);
        *(short8v*)(cA + ((base + 16) ^ s)) = *(short8v*)(h + 8);
    }
    __syncthreads();

    int l = tid & 63, wvv2 = tid >> 6;
    int n0 = wvv2 << 4;
    int lr = l & 15, lg = l >> 4;
    int ncol = n0 + lr;
    int sb_s = (ncol & 7) << 4;
    half8v bf0 = __builtin_bit_cast(half8v, *(short8v*)(cB + ((ncol * 128 + lg * 16) ^ sb_s)));
    half8v bf1 = __builtin_bit_cast(half8v, *(short8v*)(cB + ((ncol * 128 + 64 + lg * 16) ^ sb_s)));
    float bias = bb[ncol];

#pragma unroll
    for (int pl = 0; pl < 8; ++pl) {
        int re = (pl << 5) + lr;
        int sa_s = (re & 7) << 4;
        int rbase = re * 128;
        half8v ae0 = __builtin_bit_cast(half8v, *(short8v*)(cA + ((rbase + lg * 16) ^ sa_s)));
        half8v ae1 = __builtin_bit_cast(half8v, *(short8v*)(cA + ((rbase + 64 + lg * 16) ^ sa_s)));
        half8v ao0 = __builtin_bit_cast(half8v, *(short8v*)(cA + ((rbase + 2048 + lg * 16) ^ sa_s)));
        half8v ao1 = __builtin_bit_cast(half8v, *(short8v*)(cA + ((rbase + 2048 + 64 + lg * 16) ^ sa_s)));
        f32x4 acce = {0.f, 0.f, 0.f, 0.f};
        f32x4 acco = {0.f, 0.f, 0.f, 0.f};
        acce = __builtin_amdgcn_mfma_f32_16x16x32_f16(ae0, bf0, acce, 0, 0, 0);
        acce = __builtin_amdgcn_mfma_f32_16x16x32_f16(ae1, bf1, acce, 0, 0, 0);
        acco = __builtin_amdgcn_mfma_f32_16x16x32_f16(ao0, bf0, acco, 0, 0, 0);
        acco = __builtin_amdgcn_mfma_f32_16x16x32_f16(ao1, bf1, acco, 0, 0, 0);
        float mv = fmaxf(fmaxf(acce[0], acce[1]), fmaxf(acce[2], acce[3]));
        if (lg == 0) {
            float mo = fmaxf(fmaxf(acco[0], acco[1]), fmaxf(acco[2], acco[3]));
            mv = fmaxf(mv, mo);
        }
        mv = fmaxf(mv, __shfl_xor(mv, 16));
        mv = fmaxf(mv, __shfl_xor(mv, 32));
        if (l < 16) {
            int gp = p0 + pl;
            float o = mv + bias;
            xout[(size_t)gp * 64 + ncol] = o;
            hcat16[(size_t)gp * 192 + hoff + ncol] = (unsigned short)f2h(o);
        }
    }
}

// ---------------------------------------------------------------- head GEMM via MFMA, A-read-once tiling
// M-tile 64 x N-tile NT (256 or 128); 4 waves, wave w covers cols [w*NT/4, +NT/4).
// W transposed: wT[N][K]. fp16 in/out, fp32 acc. Accumulation order identical to prior kernel.
template <int RELU, int NT>
__global__ void __launch_bounds__(256) hgemm_kernel(
    const unsigned short* __restrict__ A, const unsigned short* __restrict__ wT,
    const float* __restrict__ bias, unsigned short* __restrict__ C,
    int M, int N, int K) {
    __shared__ char sA[64 * 128];        // 8 KB
    __shared__ char sB[NT * 128];        // 32 KB (NT=256) / 16 KB (NT=128)
    constexpr int NF = NT / 64;          // N-frags per wave
    int tid = threadIdx.x;
    int row0 = blockIdx.y * 64, col0 = blockIdx.x * NT;
    int w = tid >> 6, l = tid & 63;
    int lr = l & 15, lg = l >> 4;
    int wcol = w * (NT / 4);

    f32x4 acc[4][NF];
#pragma unroll
    for (int m = 0; m < 4; ++m)
#pragma unroll
        for (int n = 0; n < NF; ++n) acc[m][n] = (f32x4){0.f, 0.f, 0.f, 0.f};

    for (int kt = 0; kt < K; kt += 64) {
        for (int i = tid; i < 512; i += 256) {
            int r = i >> 3, part = i & 7;
            short8v v = *(const short8v*)(A + (size_t)(row0 + r) * K + kt + part * 8);
            *(short8v*)(sA + ((r * 128 + part * 16) ^ ((r & 7) << 4))) = v;
        }
        for (int i = tid; i < NT * 8; i += 256) {
            int r = i >> 3, part = i & 7;
            short8v v = *(const short8v*)(wT + (size_t)(col0 + r) * K + kt + part * 8);
            *(short8v*)(sB + ((r * 128 + part * 16) ^ ((r & 7) << 4))) = v;
        }
        __syncthreads();
#pragma unroll
        for (int ks = 0; ks < 2; ++ks) {
            half8v af[4], bf[NF];
#pragma unroll
            for (int m = 0; m < 4; ++m) {
                int r = m * 16 + lr;
                af[m] = __builtin_bit_cast(half8v, *(short8v*)(sA + ((r * 128 + ks * 64 + lg * 16) ^ ((r & 7) << 4))));
            }
#pragma unroll
            for (int n = 0; n < NF; ++n) {
                int c = wcol + n * 16 + lr;
                bf[n] = __builtin_bit_cast(half8v, *(short8v*)(sB + ((c * 128 + ks * 64 + lg * 16) ^ ((c & 7) << 4))));
            }
#pragma unroll
            for (int n = 0; n < NF; ++n)
#pragma unroll
                for (int m = 0; m < 4; ++m)
                    acc[m][n] = __builtin_amdgcn_mfma_f32_16x16x32_f16(af[m], bf[n], acc[m][n], 0, 0, 0);
        }
        __syncthreads();
    }
#pragma unroll
    for (int m = 0; m < 4; ++m)
#pragma unroll
        for (int n = 0; n < NF; ++n) {
            int c = col0 + wcol + n * 16 + lr;
            float bj = bias[c];
#pragma unroll
            for (int j = 0; j < 4; ++j) {
                int r = row0 + m * 16 + lg * 4 + j;
                float v = acc[m][n][j] + bj;
                if (RELU) v = fmaxf(v, 0.f);
                C[(size_t)r * N + c] = (unsigned short)f2h(v);
            }
        }
}

// ---------------------------------------------------------------- generic fp32 GEMM + bias (uv only)
template <int RELU>
__global__ void __launch_bounds__(256) gemm_kernel(
    const float* __restrict__ A, const float* __restrict__ W,
    const float* __restrict__ bias, float* __restrict__ C,
    int M, int N, int Kd) {
    __shared__ float As[64][17];
    __shared__ float Bs[16][65];
    int row0 = blockIdx.y * 64, col0 = blockIdx.x * 64;
    int tid = threadIdx.x;
    int tx = tid & 15, ty = tid >> 4;
    float acc[4][4] = {};
    for (int kt = 0; kt < Kd; kt += 16) {
        for (int i = tid; i < 1024; i += 256) {
            int m = i >> 4, k = i & 15;
            As[m][k] = A[(size_t)(row0 + m) * Kd + kt + k];
        }
        for (int i = tid; i < 1024; i += 256) {
            int k = i >> 6, n = i & 63;
            Bs[k][n] = W[(size_t)(kt + k) * N + col0 + n];
        }
        __syncthreads();
#pragma unroll
        for (int k = 0; k < 16; ++k) {
            float av[4], bv[4];
#pragma unroll
            for (int i = 0; i < 4; ++i) av[i] = As[ty * 4 + i][k];
#pragma unroll
            for (int j = 0; j < 4; ++j) bv[j] = Bs[k][tx * 4 + j];
#pragma unroll
            for (int i = 0; i < 4; ++i)
#pragma unroll
                for (int j = 0; j < 4; ++j) acc[i][j] += av[i] * bv[j];
        }
        __syncthreads();
    }
#pragma unroll
    for (int j = 0; j < 4; ++j) {
        int c = col0 + tx * 4 + j;
        float bj = bias[c];
#pragma unroll
        for (int i = 0; i < 4; ++i) {
            int r = row0 + ty * 4 + i;
            float vv = acc[i][j] + bj;
            if (RELU) vv = fmaxf(vv, 0.f);
            C[(size_t)r * N + c] = vv;
        }
    }
}

// ---------------------------------------------------------------- final 128->13 + log_softmax (fp16 input)
__global__ void __launch_bounds__(256) final_kernel(const unsigned short* __restrict__ h3,
                                                    const float* __restrict__ w,
                                                    const float* __restrict__ bias,
                                                    float* __restrict__ out, int M) {
    __shared__ float sw[128 * 13];
    __shared__ float sb[13];
    int tid = threadIdx.x;
    for (int i = tid; i < 128 * 13; i += 256) sw[i] = w[i];
    if (tid < 13) sb[tid] = bias[tid];
    __syncthreads();
    int m = blockIdx.x * 256 + tid;
    if (m >= M) return;
    const short8v* hrow = (const short8v*)(h3 + (size_t)m * 128);
    float o[13];
#pragma unroll
    for (int c = 0; c < 13; ++c) o[c] = sb[c];
    for (int k8 = 0; k8 < 16; ++k8) {
        half8v hv = __builtin_bit_cast(half8v, hrow[k8]);
        int k = k8 * 8;
#pragma unroll
        for (int j = 0; j < 8; ++j) {
            float hf = h2f(hv[j]);
#pragma unroll
            for (int c = 0; c < 13; ++c) o[c] += hf * sw[(k + j) * 13 + c];
        }
    }
    float mx = o[0];
#pragma unroll
    for (int c = 1; c < 13; ++c) mx = fmaxf(mx, o[c]);
    float s = 0.f;
#pragma unroll
    for (int c = 0; c < 13; ++c) s += expf(o[c] - mx);
    float ls = logf(s);
    float* op = out + (size_t)m * 13;
#pragma unroll
    for (int c = 0; c < 13; ++c) op[c] = o[c] - mx - ls;
}

// ---------------------------------------------------------------- launch
extern "C" void kernel_launch(void* const* d_in, const int* in_sizes, int n_in,
                              void* d_out, int out_size, void* d_ws, size_t ws_size,
                              hipStream_t stream) {
    const float* feats = (const float*)d_in[0];
    const float* pos   = (const float*)d_in[1];
    const float* w1a = (const float*)d_in[3];
    const float* b1a = (const float*)d_in[4];
    const float* w1b = (const float*)d_in[5];
    const float* b1b = (const float*)d_in[6];
    const float* w2a = (const float*)d_in[7];
    const float* b2a = (const float*)d_in[8];
    const float* w2b = (const float*)d_in[9];
    const float* b2b = (const float*)d_in[10];
    const float* w3a = (const float*)d_in[11];
    const float* b3a = (const float*)d_in[12];
    const float* w3b = (const float*)d_in[13];
    const float* b3b = (const float*)d_in[14];
    const float* hw1 = (const float*)d_in[15];
    const float* hb1 = (const float*)d_in[16];
    const float* hw2 = (const float*)d_in[17];
    const float* hb2 = (const float*)d_in[18];
    const float* hw3 = (const float*)d_in[19];
    const float* hb3 = (const float*)d_in[20];
    const float* hw4 = (const float*)d_in[21];
    const float* hb4 = (const float*)d_in[22];
    float* out = (float*)d_out;
    char* ws = (char*)d_ws;

    constexpr size_t OFF_X0  = 0;                                        // NPTS*6*4
    constexpr size_t OFF_X1  = OFF_X0 + (size_t)NPTS * 6 * 4;
    constexpr size_t OFF_X2  = OFF_X1 + (size_t)NPTS * 64 * 4;
    constexpr size_t OFF_X3  = OFF_X2 + (size_t)NPTS * 64 * 4;
    constexpr size_t OFF_H16 = OFF_X3 + (size_t)NPTS * 64 * 4;
    constexpr size_t OFF_IDX = OFF_H16 + (size_t)NPTS * 192 * 2;
    constexpr size_t OFF_XN  = OFF_IDX + (size_t)NPTS * KNN * 4;
    constexpr size_t OFF_WC  = OFF_XN + (size_t)NPTS * 4;
    constexpr size_t OFF_BC  = OFF_WC + 64 * 128 * 4;
    constexpr size_t OFF_WBT = OFF_BC + 128 * 4;
    constexpr size_t OFF_W1T = OFF_WBT + 4096 * 2;
    constexpr size_t OFF_W2T = OFF_W1T + (size_t)1024 * 192 * 2;
    constexpr size_t OFF_W3T = OFF_W2T + (size_t)256 * 1024 * 2;
    constexpr size_t OFF_XH  = OFF_W3T + (size_t)128 * 256 * 2;
    constexpr size_t OFF_XL  = OFF_XH + (size_t)NPTS * 64 * 2;
    constexpr size_t OFF_BIG = OFF_XL + (size_t)NPTS * 64 * 2;

    float* x0   = (float*)(ws + OFF_X0);
    float* x1   = (float*)(ws + OFF_X1);
    float* x2b  = (float*)(ws + OFF_X2);
    float* x3   = (float*)(ws + OFF_X3);
    unsigned short* hcat16 = (unsigned short*)(ws + OFF_H16);
    int*   idxb = (int*)(ws + OFF_IDX);
    float* xn   = (float*)(ws + OFF_XN);
    float* wc   = (float*)(ws + OFF_WC);
    float* bc   = (float*)(ws + OFF_BC);
    unsigned short* wbT = (unsigned short*)(ws + OFF_WBT);
    unsigned short* w1T = (unsigned short*)(ws + OFF_W1T);
    unsigned short* w2T = (unsigned short*)(ws + OFF_W2T);
    unsigned short* w3T = (unsigned short*)(ws + OFF_W3T);
    unsigned short* xh  = (unsigned short*)(ws + OFF_XH);
    unsigned short* xl  = (unsigned short*)(ws + OFF_XL);
    float* big  = (float*)(ws + OFF_BIG);
    float* uvb  = big;   // uv shares big with d2/head (disjoint lifetimes)

    size_t avail = (ws_size > OFF_BIG) ? ws_size - OFF_BIG : 0;
    int NB = (int)(avail / ((size_t)PTS * PTS * 4));
    if (NB < 1) NB = 1;
    if (NB > 4) NB = 4;

    build_x0_kernel<<<NPTS / 256, 256, 0, stream>>>(feats, pos, x0);
    prep_head_kernel<<<1024, 256, 0, stream>>>(hw1, hw2, hw3, w1T, w2T, w3T);

    // ---------------- layer 1 (D=6, fp32 dist) ----------------
    norm2_kernel<6><<<NPTS / 256, 256, 0, stream>>>(x0, xn);
    for (int b0 = 0; b0 < BATCH; b0 += NB) {
        int nb = BATCH - b0 < NB ? BATCH - b0 : NB;
        dist_kernel<6><<<dim3(PTS / 64, PTS / 64, nb), 256, 0, stream>>>(x0, xn, big, b0);
        topk_kernel<<<dim3(PTS / 4, nb), 256, 0, stream>>>(big, idxb, b0);
    }
    prep_kernel<<<32, 256, 0, stream>>>(w1a, b1a, w1b, wc, bc, wbT, 6);
    uv6_kernel<<<NPTS * 128 / 256, 256, 0, stream>>>(x0, wc, bc, uvb);
    edge_mfma_kernel<<<NPTS / 8, 256, 0, stream>>>(uvb, idxb, wbT, b1b, x1, hcat16, 0);

#define KNN64_PASS(XCUR)                                                                   \
    do {                                                                                   \
        norm2_kernel<64><<<NPTS / 256, 256, 0, stream>>>(XCUR, xn);                        \
        split16_kernel<<<NPTS * 64 / 4 / 256, 256, 0, stream>>>(XCUR, xh, xl);             \
        for (int b0 = 0; b0 < BATCH; b0 += NB) {                                           \
            int nb = BATCH - b0 < NB ? BATCH - b0 : NB;                                    \
            dist_mfma_kernel<<<dim3(PTS / 64, PTS / 128, nb), 256, 0, stream>>>(           \
                xh, xl, xn, big, b0);                                                      \
            topk_kernel<<<dim3(PTS / 4, nb), 256, 0, stream>>>(big, idxb, b0);             \
        }                                                                                  \
    } while (0)

    // ---------------- layer 2 (D=64) ----------------
    KNN64_PASS(x1);
    prep_kernel<<<32, 256, 0, stream>>>(w2a, b2a, w2b, wc, bc, wbT, 64);
    gemm_kernel<0><<<dim3(2, 256), 256, 0, stream>>>(x1, wc, bc, uvb, NPTS, 128, 64);
    edge_mfma_kernel<<<NPTS / 8, 256, 0, stream>>>(uvb, idxb, wbT, b2b, x2b, hcat16, 64);

    // ---------------- layer 3 (D=64) ----------------
    KNN64_PASS(x2b);
    prep_kernel<<<32, 256, 0, stream>>>(w3a, b3a, w3b, wc, bc, wbT, 64);
    gemm_kernel<0><<<dim3(2, 256), 256, 0, stream>>>(x2b, wc, bc, uvb, NPTS, 128, 64);
    edge_mfma_kernel<<<NPTS / 8, 256, 0, stream>>>(uvb, idxb, wbT, b3b, x3, hcat16, 128);

    // ---------------- head MLP (fp16 MFMA, A-read-once tiles) ----------------
    size_t need = (size_t)NPTS * (1024 + 256 + 128) * 2;
    int RCH = (avail >= need) ? NPTS : 2048;
    unsigned short* h1 = (unsigned short*)big;
    unsigned short* h2 = h1 + (size_t)RCH * 1024;
    unsigned short* h3 = h2 + (size_t)RCH * 256;
    for (int c0 = 0; c0 < NPTS; c0 += RCH) {
        const unsigned short* Ain = hcat16 + (size_t)c0 * 192;
        hgemm_kernel<1, 256><<<dim3(1024 / 256, RCH / 64), 256, 0, stream>>>(Ain, w1T, hb1, h1, RCH, 1024, 192);
        hgemm_kernel<1, 256><<<dim3(1, RCH / 64), 256, 0, stream>>>(h1, w2T, hb2, h2, RCH, 256, 1024);
        hgemm_kernel<1, 128><<<dim3(1, RCH / 64), 256, 0, stream>>>(h2, w3T, hb3, h3, RCH, 128, 256);
        final_kernel<<<RCH / 256, 256, 0, stream>>>(h3, hw4, hb4, out + (size_t)c0 * 13, RCH);
    }
#undef KNN64_PASS
}

// Round 13
// 565.722 us; speedup vs baseline: 1.0426x; 1.0426x over previous
//
#include <hip/hip_runtime.h>
#include <math.h>

#define BATCH 8
#define PTS   2048
#define NPTS  (BATCH * PTS)
#define KNN   20

typedef short short4v __attribute__((ext_vector_type(4)));
typedef short short8v __attribute__((ext_vector_type(8)));
typedef _Float16 half8v __attribute__((ext_vector_type(8)));
typedef float f32x4 __attribute__((ext_vector_type(4)));

__device__ __forceinline__ short f2h(float f) {
    _Float16 h = (_Float16)f;
    return __builtin_bit_cast(short, h);
}
__device__ __forceinline__ float h2f(_Float16 h) { return (float)h; }

// ---------------------------------------------------------------- build x0 (compact, stride 6)
__global__ void build_x0_kernel(const float* __restrict__ feats,
                                const float* __restrict__ pos,
                                float* __restrict__ x0) {
    int i = blockIdx.x * 256 + threadIdx.x;
    if (i >= NPTS) return;
    float* o = x0 + (size_t)i * 6;
    const float* f = feats + (size_t)i * 3;
    const float* p = pos + (size_t)i * 3;
    o[0] = f[0]; o[1] = f[1]; o[2] = f[2];
    o[3] = p[0]; o[4] = p[1]; o[5] = p[2];
}

// ---------------------------------------------------------------- row norms
template <int D>
__global__ void norm2_kernel(const float* __restrict__ x, float* __restrict__ xn) {
    int i = blockIdx.x * 256 + threadIdx.x;
    if (i >= NPTS) return;
    const float* r = x + (size_t)i * D;
    float s = 0.f;
#pragma unroll
    for (int j = 0; j < D; ++j) s += r[j] * r[j];
    xn[i] = s;
}

// ---------------------------------------------------------------- hi/lo fp16 split (4 elems/thread)
__global__ void split16_kernel(const float* __restrict__ x, unsigned short* __restrict__ xh,
                               unsigned short* __restrict__ xl) {
    int i = blockIdx.x * 256 + threadIdx.x;   // over NPTS*64/4
    float4 v = ((const float4*)x)[i];
    float vv[4] = {v.x, v.y, v.z, v.w};
    short4v hh, ll;
#pragma unroll
    for (int j = 0; j < 4; ++j) {
        _Float16 hf = (_Float16)vv[j];
        hh[j] = __builtin_bit_cast(short, hf);
        _Float16 lf = (_Float16)(vv[j] - (float)hf);
        ll[j] = __builtin_bit_cast(short, lf);
    }
    ((short4v*)xh)[i] = hh;
    ((short4v*)xl)[i] = ll;
}

// ---------------------------------------------------------------- pairwise d2, fp32 VALU (D=6 layer)
template <int D>
__global__ void __launch_bounds__(256) dist_kernel(const float* __restrict__ x,
                                                   const float* __restrict__ xn,
                                                   float* __restrict__ d2, int b0) {
    int bz = blockIdx.z;
    int b  = b0 + bz;
    const float* xb  = x  + (size_t)b * PTS * D;
    const float* xnb = xn + (size_t)b * PTS;
    float* d2b = d2 + (size_t)bz * PTS * PTS;

    __shared__ float As[64][D + 1];
    __shared__ float Bs[64][D + 1];
    int row0 = blockIdx.y * 64;
    int col0 = blockIdx.x * 64;
    int tid = threadIdx.x;
    for (int i = tid; i < 64 * D; i += 256) {
        int r = i / D, c = i - r * D;
        As[r][c] = xb[(size_t)(row0 + r) * D + c];
        Bs[r][c] = xb[(size_t)(col0 + r) * D + c];
    }
    __syncthreads();
    int tx = tid & 15, ty = tid >> 4;
    float acc[4][4] = {};
    for (int k = 0; k < D; ++k) {
        float av[4], bv[4];
#pragma unroll
        for (int i = 0; i < 4; ++i) av[i] = As[ty * 4 + i][k];
#pragma unroll
        for (int j = 0; j < 4; ++j) bv[j] = Bs[tx * 4 + j][k];
#pragma unroll
        for (int i = 0; i < 4; ++i)
#pragma unroll
            for (int j = 0; j < 4; ++j) acc[i][j] += av[i] * bv[j];
    }
#pragma unroll
    for (int i = 0; i < 4; ++i) {
        int r = row0 + ty * 4 + i;
#pragma unroll
        for (int j = 0; j < 4; ++j) {
            int c = col0 + tx * 4 + j;
            d2b[(size_t)r * PTS + c] = xnb[c] - 2.f * acc[i][j];
        }
    }
}

// ---------------------------------------------------------------- pairwise d2 via MFMA hi/lo fp16 (D=64)
__global__ void __launch_bounds__(256) dist_mfma_kernel(
    const unsigned short* __restrict__ xh, const unsigned short* __restrict__ xl,
    const float* __restrict__ xn, float* __restrict__ d2, int b0)
{
    __shared__ char smem[128 * 256 + 64 * 256];   // 48KB: A(32K) | B(16K)
    __shared__ float sxn[64];
    char* sA = smem;
    char* sB = smem + 128 * 256;
    float* sS = (float*)smem;                     // reused after compute
    int bz = blockIdx.z, b = b0 + bz;
    int row0 = blockIdx.y * 128, col0 = blockIdx.x * 64;
    const unsigned short* xhb = xh + (size_t)b * PTS * 64;
    const unsigned short* xlb = xl + (size_t)b * PTS * 64;
    const float* xnb = xn + (size_t)b * PTS;
    float* d2b = d2 + (size_t)bz * PTS * PTS;
    int tid = threadIdx.x;

    for (int i = tid; i < 2048; i += 256) {
        int r = i >> 4, c = i & 15;
        const unsigned short* src = (c < 8) ? xhb + (size_t)(row0 + r) * 64 + (c << 3)
                                            : xlb + (size_t)(row0 + r) * 64 + ((c - 8) << 3);
        *(short8v*)(sA + ((r * 256 + (c << 4)) ^ ((r & 7) << 4))) = *(const short8v*)src;
    }
    for (int i = tid; i < 1024; i += 256) {
        int r = i >> 4, c = i & 15;
        const unsigned short* src = (c < 8) ? xhb + (size_t)(col0 + r) * 64 + (c << 3)
                                            : xlb + (size_t)(col0 + r) * 64 + ((c - 8) << 3);
        *(short8v*)(sB + ((r * 256 + (c << 4)) ^ ((r & 7) << 4))) = *(const short8v*)src;
    }
    if (tid < 64) sxn[tid] = xnb[col0 + tid];
    __syncthreads();

    int w = tid >> 6, l = tid & 63;
    int lr = l & 15, lg = l >> 4;

    half8v bh[4][2], bl[4][2];
#pragma unroll
    for (int n = 0; n < 4; ++n) {
        int c = n * 16 + lr, sw = (c & 7) << 4, base = c * 256;
#pragma unroll
        for (int ks = 0; ks < 2; ++ks) {
            bh[n][ks] = __builtin_bit_cast(half8v, *(short8v*)(sB + ((base + ks * 64 + lg * 16) ^ sw)));
            bl[n][ks] = __builtin_bit_cast(half8v, *(short8v*)(sB + ((base + 128 + ks * 64 + lg * 16) ^ sw)));
        }
    }

    f32x4 acc[2][4];
#pragma unroll
    for (int m = 0; m < 2; ++m)
#pragma unroll
        for (int n = 0; n < 4; ++n) acc[m][n] = (f32x4){0.f, 0.f, 0.f, 0.f};

#pragma unroll
    for (int m = 0; m < 2; ++m) {
        int r = w * 32 + m * 16 + lr, sw = (r & 7) << 4, base = r * 256;
        half8v ah0 = __builtin_bit_cast(half8v, *(short8v*)(sA + ((base + lg * 16) ^ sw)));
        half8v ah1 = __builtin_bit_cast(half8v, *(short8v*)(sA + ((base + 64 + lg * 16) ^ sw)));
        half8v al0 = __builtin_bit_cast(half8v, *(short8v*)(sA + ((base + 128 + lg * 16) ^ sw)));
        half8v al1 = __builtin_bit_cast(half8v, *(short8v*)(sA + ((base + 192 + lg * 16) ^ sw)));
#pragma unroll
        for (int n = 0; n < 4; ++n) {
            f32x4 a = acc[m][n];
            a = __builtin_amdgcn_mfma_f32_16x16x32_f16(ah0, bh[n][0], a, 0, 0, 0);
            a = __builtin_amdgcn_mfma_f32_16x16x32_f16(ah1, bh[n][1], a, 0, 0, 0);
            a = __builtin_amdgcn_mfma_f32_16x16x32_f16(al0, bh[n][0], a, 0, 0, 0);
            a = __builtin_amdgcn_mfma_f32_16x16x32_f16(al1, bh[n][1], a, 0, 0, 0);
            a = __builtin_amdgcn_mfma_f32_16x16x32_f16(ah0, bl[n][0], a, 0, 0, 0);
            a = __builtin_amdgcn_mfma_f32_16x16x32_f16(ah1, bl[n][1], a, 0, 0, 0);
            acc[m][n] = a;
        }
    }
    __syncthreads();   // all sA/sB reads complete; safe to reuse as sS

#pragma unroll
    for (int m = 0; m < 2; ++m)
#pragma unroll
        for (int n = 0; n < 4; ++n) {
            int rl = w * 32 + m * 16 + lg * 4;
            int col = n * 16 + lr;
#pragma unroll
            for (int j = 0; j < 4; ++j)
                sS[(rl + j) * 64 + col] = acc[m][n][j];
        }
    __syncthreads();

    for (int i = tid; i < 2048; i += 256) {
        int r = i >> 4, c4 = (i & 15) << 2;
        float4 v = *(float4*)&sS[r * 64 + c4];
        float4 o;
        o.x = sxn[c4 + 0] - 2.f * v.x;
        o.y = sxn[c4 + 1] - 2.f * v.y;
        o.z = sxn[c4 + 2] - 2.f * v.z;
        o.w = sxn[c4 + 3] - 2.f * v.w;
        *(float4*)&d2b[(size_t)(row0 + r) * PTS + col0 + c4] = o;
    }
}

// ---------------------------------------------------------------- top-K smallest, 1 wave/row, reg-resident
#define GMIN8(B, GV, GJ) do {                                         \
    GV = va[(B)];     GJ = (B);                                       \
    if (va[(B)+1] < GV) { GV = va[(B)+1]; GJ = (B)+1; }               \
    if (va[(B)+2] < GV) { GV = va[(B)+2]; GJ = (B)+2; }               \
    if (va[(B)+3] < GV) { GV = va[(B)+3]; GJ = (B)+3; }               \
    if (va[(B)+4] < GV) { GV = va[(B)+4]; GJ = (B)+4; }               \
    if (va[(B)+5] < GV) { GV = va[(B)+5]; GJ = (B)+5; }               \
    if (va[(B)+6] < GV) { GV = va[(B)+6]; GJ = (B)+6; }               \
    if (va[(B)+7] < GV) { GV = va[(B)+7]; GJ = (B)+7; }               \
} while (0)

#define INVAL8(B, GV, GJ, JS) do {                                    \
    va[(B)+0] = ((B)+0 == (JS)) ? INFV : va[(B)+0];                   \
    va[(B)+1] = ((B)+1 == (JS)) ? INFV : va[(B)+1];                   \
    va[(B)+2] = ((B)+2 == (JS)) ? INFV : va[(B)+2];                   \
    va[(B)+3] = ((B)+3 == (JS)) ? INFV : va[(B)+3];                   \
    va[(B)+4] = ((B)+4 == (JS)) ? INFV : va[(B)+4];                   \
    va[(B)+5] = ((B)+5 == (JS)) ? INFV : va[(B)+5];                   \
    va[(B)+6] = ((B)+6 == (JS)) ? INFV : va[(B)+6];                   \
    va[(B)+7] = ((B)+7 == (JS)) ? INFV : va[(B)+7];                   \
    GMIN8(B, GV, GJ);                                                 \
} while (0)

__global__ void __launch_bounds__(256) topk_kernel(const float* __restrict__ d2,
                                                   int* __restrict__ nbr, int b0) {
    const float INFV = __builtin_inff();
    int wid = threadIdx.x >> 6, lane = threadIdx.x & 63;
    int pl = blockIdx.x * 4 + wid;
    int bz = blockIdx.y;
    const float* row = d2 + ((size_t)bz * PTS + pl) * PTS;

    float va[32];
#pragma unroll
    for (int j8 = 0; j8 < 8; ++j8) {
        float4 v = *(const float4*)&row[j8 * 256 + lane * 4];
        va[j8 * 4 + 0] = v.x; va[j8 * 4 + 1] = v.y;
        va[j8 * 4 + 2] = v.z; va[j8 * 4 + 3] = v.w;
    }

    float g0v, g1v, g2v, g3v;
    int   g0j, g1j, g2j, g3j;
    GMIN8(0,  g0v, g0j);
    GMIN8(8,  g1v, g1j);
    GMIN8(16, g2v, g2j);
    GMIN8(24, g3v, g3j);

    int gbase = (b0 + bz) * PTS;
    int* outp = nbr + (size_t)(gbase + pl) * KNN;

    for (int k = 0; k < KNN; ++k) {
        float lv = g0v; int lj = g0j;
        if (g1v < lv) { lv = g1v; lj = g1j; }
        if (g2v < lv) { lv = g2v; lj = g2j; }
        if (g3v < lv) { lv = g3v; lj = g3j; }
        float wm = lv;
#pragma unroll
        for (int off = 1; off < 64; off <<= 1) wm = fminf(wm, __shfl_xor(wm, off));
        int mycol = (lv == wm) ? (((lj >> 2) << 8) | (lane << 2) | (lj & 3)) : 0x7fffffff;
        int wc = mycol;
#pragma unroll
        for (int off = 1; off < 64; off <<= 1) {
            int oc = __shfl_xor(wc, off);
            wc = oc < wc ? oc : wc;
        }
        if (lane == 0) outp[k] = gbase + wc;
        if (mycol == wc) {
            int js = lj;
            int gs = js >> 3;
            if (gs == 0)      INVAL8(0,  g0v, g0j, js);
            else if (gs == 1) INVAL8(8,  g1v, g1j, js);
            else if (gs == 2) INVAL8(16, g2v, g2j, js);
            else              INVAL8(24, g3v, g3j, js);
        }
    }
}

// ---------------------------------------------------------------- per-layer weight prep
__global__ void prep_kernel(const float* __restrict__ wa, const float* __restrict__ ba,
                            const float* __restrict__ wb,
                            float* __restrict__ wc, float* __restrict__ bc,
                            unsigned short* __restrict__ wbT, int D) {
    int t = blockIdx.x * 256 + threadIdx.x;
    if (t < D * 128) {
        int k = t >> 7, n = t & 127;
        wc[t] = (n < 64) ? (wa[k * 64 + n] - wa[(D + k) * 64 + n])
                         : wa[(D + k) * 64 + (n - 64)];
    }
    if (t < 128) bc[t] = (t < 64) ? ba[t] : 0.f;
    if (t < 4096) {
        int n = t >> 6, k = t & 63;
        wbT[t] = (unsigned short)f2h(wb[k * 64 + n]);
    }
}

// ---------------------------------------------------------------- head weight prep (transposed fp16)
__global__ void prep_head_kernel(const float* __restrict__ hw1, const float* __restrict__ hw2,
                                 const float* __restrict__ hw3,
                                 unsigned short* __restrict__ w1T, unsigned short* __restrict__ w2T,
                                 unsigned short* __restrict__ w3T) {
    int t = blockIdx.x * 256 + threadIdx.x;
    if (t < 192 * 1024) { int k = t / 1024, n = t - k * 1024; w1T[n * 192 + k] = (unsigned short)f2h(hw1[t]); }
    if (t < 1024 * 256) { int k = t >> 8, n = t & 255; w2T[n * 1024 + k] = (unsigned short)f2h(hw2[t]); }
    if (t < 256 * 128)  { int k = t >> 7, n = t & 127; w3T[n * 256 + k] = (unsigned short)f2h(hw3[t]); }
}

// ---------------------------------------------------------------- uv for layer 1 (D=6, compact x0)
__global__ void uv6_kernel(const float* __restrict__ x0, const float* __restrict__ wc,
                           const float* __restrict__ bc, float* __restrict__ uvout) {
    int t = blockIdx.x * 256 + threadIdx.x;
    int i = t >> 7, n = t & 127;
    const float* xr = x0 + (size_t)i * 6;
    float s = bc[n];
#pragma unroll
    for (int r = 0; r < 6; ++r) s += xr[r] * wc[r * 128 + n];
    uvout[t] = s;
}

// ---------------------------------------------------------------- EdgeConv via MFMA (fp16)
__global__ void __launch_bounds__(256) edge_mfma_kernel(
    const float* __restrict__ uv, const int* __restrict__ nbr,
    const unsigned short* __restrict__ wbT, const float* __restrict__ bb,
    float* __restrict__ xout, unsigned short* __restrict__ hcat16, int hoff)
{
    __shared__ short sA[256 * 64];   // 32 KB, swizzled
    __shared__ short sB[64 * 64];    // 8 KB, swizzled (holds wbT)
    __shared__ int snbr[8 * KNN];
    char* cA = (char*)sA;
    char* cB = (char*)sB;
    int tid = threadIdx.x;
    int p0 = blockIdx.x * 8;

    if (tid < 8 * KNN) snbr[tid] = nbr[(size_t)p0 * KNN + tid];
    for (int c = tid; c < 512; c += 256) {
        int n = c >> 3, k0 = (c & 7) << 3;
        short8v w = *(const short8v*)(wbT + n * 64 + k0);
        *(short8v*)(cB + ((n * 128 + (k0 << 1)) ^ ((n & 7) << 4))) = w;
    }
    __syncthreads();

    for (int t = tid; t < 1024; t += 256) {
        int r = t >> 2, c16 = (t & 3) << 4;
        int pl = r >> 5, e = r & 31;
        short h[16] __attribute__((aligned(16)));
        if (e < KNN) {
            int q = snbr[pl * KNN + e];
            const float4* up = (const float4*)(uv + (size_t)(p0 + pl) * 128 + c16);
            const float4* vp = (const float4*)(uv + (size_t)q * 128 + 64 + c16);
#pragma unroll
            for (int j = 0; j < 4; ++j) {
                float4 uu = up[j], vv = vp[j];
                h[j * 4 + 0] = f2h(fmaxf(uu.x + vv.x, 0.f));
                h[j * 4 + 1] = f2h(fmaxf(uu.y + vv.y, 0.f));
                h[j * 4 + 2] = f2h(fmaxf(uu.z + vv.z, 0.f));
                h[j * 4 + 3] = f2h(fmaxf(uu.w + vv.w, 0.f));
            }
        } else {
#pragma unroll
            for (int j = 0; j < 16; ++j) h[j] = 0;
        }
        int base = r * 128 + (c16 << 1);
        int s = (r & 7) << 4;
        *(short8v*)(cA + (base ^ s)) = *(short8v*)(h);
        *(short8v*)(cA + ((base + 16) ^ s)) = *(short8v*)(h + 8);
    }
    __syncthreads();

    int l = tid & 63, wvv2 = tid >> 6;
    int n0 = wvv2 << 4;
    int lr = l & 15, lg = l >> 4;
    int ncol = n0 + lr;
    int sb_s = (ncol & 7) << 4;
    half8v bf0 = __builtin_bit_cast(half8v, *(short8v*)(cB + ((ncol * 128 + lg * 16) ^ sb_s)));
    half8v bf1 = __builtin_bit_cast(half8v, *(short8v*)(cB + ((ncol * 128 + 64 + lg * 16) ^ sb_s)));
    float bias = bb[ncol];

#pragma unroll
    for (int pl = 0; pl < 8; ++pl) {
        int re = (pl << 5) + lr;
        int sa_s = (re & 7) << 4;
        int rbase = re * 128;
        half8v ae0 = __builtin_bit_cast(half8v, *(short8v*)(cA + ((rbase + lg * 16) ^ sa_s)));
        half8v ae1 = __builtin_bit_cast(half8v, *(short8v*)(cA + ((rbase + 64 + lg * 16) ^ sa_s)));
        half8v ao0 = __builtin_bit_cast(half8v, *(short8v*)(cA + ((rbase + 2048 + lg * 16) ^ sa_s)));
        half8v ao1 = __builtin_bit_cast(half8v, *(short8v*)(cA + ((rbase + 2048 + 64 + lg * 16) ^ sa_s)));
        f32x4 acce = {0.f, 0.f, 0.f, 0.f};
        f32x4 acco = {0.f, 0.f, 0.f, 0.f};
        acce = __builtin_amdgcn_mfma_f32_16x16x32_f16(ae0, bf0, acce, 0, 0, 0);
        acce = __builtin_amdgcn_mfma_f32_16x16x32_f16(ae1, bf1, acce, 0, 0, 0);
        acco = __builtin_amdgcn_mfma_f32_16x16x32_f16(ao0, bf0, acco, 0, 0, 0);
        acco = __builtin_amdgcn_mfma_f32_16x16x32_f16(ao1, bf1, acco, 0, 0, 0);
        float mv = fmaxf(fmaxf(acce[0], acce[1]), fmaxf(acce[2], acce[3]));
        if (lg == 0) {
            float mo = fmaxf(fmaxf(acco[0], acco[1]), fmaxf(acco[2], acco[3]));
            mv = fmaxf(mv, mo);
        }
        mv = fmaxf(mv, __shfl_xor(mv, 16));
        mv = fmaxf(mv, __shfl_xor(mv, 32));
        if (l < 16) {
            int gp = p0 + pl;
            float o = mv + bias;
            xout[(size_t)gp * 64 + ncol] = o;
            hcat16[(size_t)gp * 192 + hoff + ncol] = (unsigned short)f2h(o);
        }
    }
}

// ---------------------------------------------------------------- head GEMM via MFMA (fp16 in/out, fp32 acc)
// 128x64 C-tile (round-11 shape) + XCD-aware block swizzle: remap linear id so each
// XCD gets a contiguous logical range -> the 4..16 col-blocks sharing an A-panel run
// on ONE XCD, A-panel fetched from HBM once. Requires nwg % 8 == 0 (all head grids).
template <int RELU>
__global__ void __launch_bounds__(256) hgemm_kernel(
    const unsigned short* __restrict__ A, const unsigned short* __restrict__ wT,
    const float* __restrict__ bias, unsigned short* __restrict__ C,
    int M, int N, int K) {
    __shared__ char sA[128 * 128];
    __shared__ char sB[64 * 128];
    int tid = threadIdx.x;

    int nwg = gridDim.x * gridDim.y;
    int lid = blockIdx.y * gridDim.x + blockIdx.x;
    int cpx = nwg >> 3;                              // nwg % 8 == 0 guaranteed
    int logical = (lid & 7) * cpx + (lid >> 3);
    int bx = logical % gridDim.x, by = logical / gridDim.x;

    int row0 = by * 128, col0 = bx * 64;
    int w = tid >> 6, l = tid & 63;
    int lr = l & 15, lg = l >> 4;

    f32x4 acc[2][4];
#pragma unroll
    for (int m = 0; m < 2; ++m)
#pragma unroll
        for (int n = 0; n < 4; ++n) acc[m][n] = (f32x4){0.f, 0.f, 0.f, 0.f};

    for (int kt = 0; kt < K; kt += 64) {
        for (int i = tid; i < 1024; i += 256) {
            int r = i >> 3, part = i & 7;
            short8v v = *(const short8v*)(A + (size_t)(row0 + r) * K + kt + part * 8);
            *(short8v*)(sA + ((r * 128 + part * 16) ^ ((r & 7) << 4))) = v;
        }
        for (int i = tid; i < 512; i += 256) {
            int r = i >> 3, part = i & 7;
            short8v v = *(const short8v*)(wT + (size_t)(col0 + r) * K + kt + part * 8);
            *(short8v*)(sB + ((r * 128 + part * 16) ^ ((r & 7) << 4))) = v;
        }
        __syncthreads();
#pragma unroll
        for (int ks = 0; ks < 2; ++ks) {
            half8v af0, af1, bf[4];
            {
                int r = w * 32 + lr;
                af0 = __builtin_bit_cast(half8v, *(short8v*)(sA + ((r * 128 + ks * 64 + lg * 16) ^ ((r & 7) << 4))));
                int r2 = r + 16;
                af1 = __builtin_bit_cast(half8v, *(short8v*)(sA + ((r2 * 128 + ks * 64 + lg * 16) ^ ((r2 & 7) << 4))));
            }
#pragma unroll
            for (int n = 0; n < 4; ++n) {
                int c = n * 16 + lr;
                bf[n] = __builtin_bit_cast(half8v, *(short8v*)(sB + ((c * 128 + ks * 64 + lg * 16) ^ ((c & 7) << 4))));
            }
#pragma unroll
            for (int n = 0; n < 4; ++n) {
                acc[0][n] = __builtin_amdgcn_mfma_f32_16x16x32_f16(af0, bf[n], acc[0][n], 0, 0, 0);
                acc[1][n] = __builtin_amdgcn_mfma_f32_16x16x32_f16(af1, bf[n], acc[1][n], 0, 0, 0);
            }
        }
        __syncthreads();
    }
#pragma unroll
    for (int m = 0; m < 2; ++m)
#pragma unroll
        for (int n = 0; n < 4; ++n) {
            int c = col0 + n * 16 + lr;
            float bj = bias[c];
#pragma unroll
            for (int j = 0; j < 4; ++j) {
                int r = row0 + w * 32 + m * 16 + lg * 4 + j;
                float v = acc[m][n][j] + bj;
                if (RELU) v = fmaxf(v, 0.f);
                C[(size_t)r * N + c] = (unsigned short)f2h(v);
            }
        }
}

// ---------------------------------------------------------------- generic fp32 GEMM + bias (uv only)
template <int RELU>
__global__ void __launch_bounds__(256) gemm_kernel(
    const float* __restrict__ A, const float* __restrict__ W,
    const float* __restrict__ bias, float* __restrict__ C,
    int M, int N, int Kd) {
    __shared__ float As[64][17];
    __shared__ float Bs[16][65];
    int row0 = blockIdx.y * 64, col0 = blockIdx.x * 64;
    int tid = threadIdx.x;
    int tx = tid & 15, ty = tid >> 4;
    float acc[4][4] = {};
    for (int kt = 0; kt < Kd; kt += 16) {
        for (int i = tid; i < 1024; i += 256) {
            int m = i >> 4, k = i & 15;
            As[m][k] = A[(size_t)(row0 + m) * Kd + kt + k];
        }
        for (int i = tid; i < 1024; i += 256) {
            int k = i >> 6, n = i & 63;
            Bs[k][n] = W[(size_t)(kt + k) * N + col0 + n];
        }
        __syncthreads();
#pragma unroll
        for (int k = 0; k < 16; ++k) {
            float av[4], bv[4];
#pragma unroll
            for (int i = 0; i < 4; ++i) av[i] = As[ty * 4 + i][k];
#pragma unroll
            for (int j = 0; j < 4; ++j) bv[j] = Bs[k][tx * 4 + j];
#pragma unroll
            for (int i = 0; i < 4; ++i)
#pragma unroll
                for (int j = 0; j < 4; ++j) acc[i][j] += av[i] * bv[j];
        }
        __syncthreads();
    }
#pragma unroll
    for (int j = 0; j < 4; ++j) {
        int c = col0 + tx * 4 + j;
        float bj = bias[c];
#pragma unroll
        for (int i = 0; i < 4; ++i) {
            int r = row0 + ty * 4 + i;
            float vv = acc[i][j] + bj;
            if (RELU) vv = fmaxf(vv, 0.f);
            C[(size_t)r * N + c] = vv;
        }
    }
}

// ---------------------------------------------------------------- final 128->13 + log_softmax (fp16 input)
__global__ void __launch_bounds__(256) final_kernel(const unsigned short* __restrict__ h3,
                                                    const float* __restrict__ w,
                                                    const float* __restrict__ bias,
                                                    float* __restrict__ out, int M) {
    __shared__ float sw[128 * 13];
    __shared__ float sb[13];
    int tid = threadIdx.x;
    for (int i = tid; i < 128 * 13; i += 256) sw[i] = w[i];
    if (tid < 13) sb[tid] = bias[tid];
    __syncthreads();
    int m = blockIdx.x * 256 + tid;
    if (m >= M) return;
    const short8v* hrow = (const short8v*)(h3 + (size_t)m * 128);
    float o[13];
#pragma unroll
    for (int c = 0; c < 13; ++c) o[c] = sb[c];
    for (int k8 = 0; k8 < 16; ++k8) {
        half8v hv = __builtin_bit_cast(half8v, hrow[k8]);
        int k = k8 * 8;
#pragma unroll
        for (int j = 0; j < 8; ++j) {
            float hf = h2f(hv[j]);
#pragma unroll
            for (int c = 0; c < 13; ++c) o[c] += hf * sw[(k + j) * 13 + c];
        }
    }
    float mx = o[0];
#pragma unroll
    for (int c = 1; c < 13; ++c) mx = fmaxf(mx, o[c]);
    float s = 0.f;
#pragma unroll
    for (int c = 0; c < 13; ++c) s += expf(o[c] - mx);
    float ls = logf(s);
    float* op = out + (size_t)m * 13;
#pragma unroll
    for (int c = 0; c < 13; ++c) op[c] = o[c] - mx - ls;
}

// ---------------------------------------------------------------- launch
extern "C" void kernel_launch(void* const* d_in, const int* in_sizes, int n_in,
                              void* d_out, int out_size, void* d_ws, size_t ws_size,
                              hipStream_t stream) {
    const float* feats = (const float*)d_in[0];
    const float* pos   = (const float*)d_in[1];
    const float* w1a = (const float*)d_in[3];
    const float* b1a = (const float*)d_in[4];
    const float* w1b = (const float*)d_in[5];
    const float* b1b = (const float*)d_in[6];
    const float* w2a = (const float*)d_in[7];
    const float* b2a = (const float*)d_in[8];
    const float* w2b = (const float*)d_in[9];
    const float* b2b = (const float*)d_in[10];
    const float* w3a = (const float*)d_in[11];
    const float* b3a = (const float*)d_in[12];
    const float* w3b = (const float*)d_in[13];
    const float* b3b = (const float*)d_in[14];
    const float* hw1 = (const float*)d_in[15];
    const float* hb1 = (const float*)d_in[16];
    const float* hw2 = (const float*)d_in[17];
    const float* hb2 = (const float*)d_in[18];
    const float* hw3 = (const float*)d_in[19];
    const float* hb3 = (const float*)d_in[20];
    const float* hw4 = (const float*)d_in[21];
    const float* hb4 = (const float*)d_in[22];
    float* out = (float*)d_out;
    char* ws = (char*)d_ws;

    constexpr size_t OFF_X0  = 0;                                        // NPTS*6*4
    constexpr size_t OFF_X1  = OFF_X0 + (size_t)NPTS * 6 * 4;
    constexpr size_t OFF_X2  = OFF_X1 + (size_t)NPTS * 64 * 4;
    constexpr size_t OFF_X3  = OFF_X2 + (size_t)NPTS * 64 * 4;
    constexpr size_t OFF_H16 = OFF_X3 + (size_t)NPTS * 64 * 4;
    constexpr size_t OFF_IDX = OFF_H16 + (size_t)NPTS * 192 * 2;
    constexpr size_t OFF_XN  = OFF_IDX + (size_t)NPTS * KNN * 4;
    constexpr size_t OFF_WC  = OFF_XN + (size_t)NPTS * 4;
    constexpr size_t OFF_BC  = OFF_WC + 64 * 128 * 4;
    constexpr size_t OFF_WBT = OFF_BC + 128 * 4;
    constexpr size_t OFF_W1T = OFF_WBT + 4096 * 2;
    constexpr size_t OFF_W2T = OFF_W1T + (size_t)1024 * 192 * 2;
    constexpr size_t OFF_W3T = OFF_W2T + (size_t)256 * 1024 * 2;
    constexpr size_t OFF_XH  = OFF_W3T + (size_t)128 * 256 * 2;
    constexpr size_t OFF_XL  = OFF_XH + (size_t)NPTS * 64 * 2;
    constexpr size_t OFF_BIG = OFF_XL + (size_t)NPTS * 64 * 2;

    float* x0   = (float*)(ws + OFF_X0);
    float* x1   = (float*)(ws + OFF_X1);
    float* x2b  = (float*)(ws + OFF_X2);
    float* x3   = (float*)(ws + OFF_X3);
    unsigned short* hcat16 = (unsigned short*)(ws + OFF_H16);
    int*   idxb = (int*)(ws + OFF_IDX);
    float* xn   = (float*)(ws + OFF_XN);
    float* wc   = (float*)(ws + OFF_WC);
    float* bc   = (float*)(ws + OFF_BC);
    unsigned short* wbT = (unsigned short*)(ws + OFF_WBT);
    unsigned short* w1T = (unsigned short*)(ws + OFF_W1T);
    unsigned short* w2T = (unsigned short*)(ws + OFF_W2T);
    unsigned short* w3T = (unsigned short*)(ws + OFF_W3T);
    unsigned short* xh  = (unsigned short*)(ws + OFF_XH);
    unsigned short* xl  = (unsigned short*)(ws + OFF_XL);
    float* big  = (float*)(ws + OFF_BIG);
    float* uvb  = big;   // uv shares big with d2/head (disjoint lifetimes)

    size_t avail = (ws_size > OFF_BIG) ? ws_size - OFF_BIG : 0;
    int NB = (int)(avail / ((size_t)PTS * PTS * 4));
    if (NB < 1) NB = 1;
    if (NB > 4) NB = 4;

    build_x0_kernel<<<NPTS / 256, 256, 0, stream>>>(feats, pos, x0);
    prep_head_kernel<<<1024, 256, 0, stream>>>(hw1, hw2, hw3, w1T, w2T, w3T);

    // ---------------- layer 1 (D=6, fp32 dist) ----------------
    norm2_kernel<6><<<NPTS / 256, 256, 0, stream>>>(x0, xn);
    for (int b0 = 0; b0 < BATCH; b0 += NB) {
        int nb = BATCH - b0 < NB ? BATCH - b0 : NB;
        dist_kernel<6><<<dim3(PTS / 64, PTS / 64, nb), 256, 0, stream>>>(x0, xn, big, b0);
        topk_kernel<<<dim3(PTS / 4, nb), 256, 0, stream>>>(big, idxb, b0);
    }
    prep_kernel<<<32, 256, 0, stream>>>(w1a, b1a, w1b, wc, bc, wbT, 6);
    uv6_kernel<<<NPTS * 128 / 256, 256, 0, stream>>>(x0, wc, bc, uvb);
    edge_mfma_kernel<<<NPTS / 8, 256, 0, stream>>>(uvb, idxb, wbT, b1b, x1, hcat16, 0);

#define KNN64_PASS(XCUR)                                                                   \
    do {                                                                                   \
        norm2_kernel<64><<<NPTS / 256, 256, 0, stream>>>(XCUR, xn);                        \
        split16_kernel<<<NPTS * 64 / 4 / 256, 256, 0, stream>>>(XCUR, xh, xl);             \
        for (int b0 = 0; b0 < BATCH; b0 += NB) {                                           \
            int nb = BATCH - b0 < NB ? BATCH - b0 : NB;                                    \
            dist_mfma_kernel<<<dim3(PTS / 64, PTS / 128, nb), 256, 0, stream>>>(           \
                xh, xl, xn, big, b0);                                                      \
            topk_kernel<<<dim3(PTS / 4, nb), 256, 0, stream>>>(big, idxb, b0);             \
        }                                                                                  \
    } while (0)

    // ---------------- layer 2 (D=64) ----------------
    KNN64_PASS(x1);
    prep_kernel<<<32, 256, 0, stream>>>(w2a, b2a, w2b, wc, bc, wbT, 64);
    gemm_kernel<0><<<dim3(2, 256), 256, 0, stream>>>(x1, wc, bc, uvb, NPTS, 128, 64);
    edge_mfma_kernel<<<NPTS / 8, 256, 0, stream>>>(uvb, idxb, wbT, b2b, x2b, hcat16, 64);

    // ---------------- layer 3 (D=64) ----------------
    KNN64_PASS(x2b);
    prep_kernel<<<32, 256, 0, stream>>>(w3a, b3a, w3b, wc, bc, wbT, 64);
    gemm_kernel<0><<<dim3(2, 256), 256, 0, stream>>>(x2b, wc, bc, uvb, NPTS, 128, 64);
    edge_mfma_kernel<<<NPTS / 8, 256, 0, stream>>>(uvb, idxb, wbT, b3b, x3, hcat16, 128);

    // ---------------- head MLP (fp16 MFMA, 128x64 tiles + XCD swizzle) ----------------
    size_t need = (size_t)NPTS * (1024 + 256 + 128) * 2;
    int RCH = (avail >= need) ? NPTS : 2048;
    unsigned short* h1 = (unsigned short*)big;
    unsigned short* h2 = h1 + (size_t)RCH * 1024;
    unsigned short* h3 = h2 + (size_t)RCH * 256;
    for (int c0 = 0; c0 < NPTS; c0 += RCH) {
        const unsigned short* Ain = hcat16 + (size_t)c0 * 192;
        hgemm_kernel<1><<<dim3(1024 / 64, RCH / 128), 256, 0, stream>>>(Ain, w1T, hb1, h1, RCH, 1024, 192);
        hgemm_kernel<1><<<dim3(256 / 64, RCH / 128), 256, 0, stream>>>(h1, w2T, hb2, h2, RCH, 256, 1024);
        hgemm_kernel<1><<<dim3(128 / 64, RCH / 128), 256, 0, stream>>>(h2, w3T, hb3, h3, RCH, 128, 256);
        final_kernel<<<RCH / 256, 256, 0, stream>>>(h3, hw4, hb4, out + (size_t)c0 * 13, RCH);
    }
#undef KNN64_PASS
}

// Round 14
// 496.980 us; speedup vs baseline: 1.1868x; 1.1383x over previous
//
#include <hip/hip_runtime.h>
#include <math.h>

#define BATCH 8
#define PTS   2048
#define NPTS  (BATCH * PTS)
#define KNN   20

typedef short short4v __attribute__((ext_vector_type(4)));
typedef short short8v __attribute__((ext_vector_type(8)));
typedef _Float16 half8v __attribute__((ext_vector_type(8)));
typedef float f32x4 __attribute__((ext_vector_type(4)));

__device__ __forceinline__ short f2h(float f) {
    _Float16 h = (_Float16)f;
    return __builtin_bit_cast(short, h);
}
__device__ __forceinline__ float h2f(_Float16 h) { return (float)h; }

// ---------------------------------------------------------------- build x0 (compact, stride 6)
__global__ void build_x0_kernel(const float* __restrict__ feats,
                                const float* __restrict__ pos,
                                float* __restrict__ x0) {
    int i = blockIdx.x * 256 + threadIdx.x;
    if (i >= NPTS) return;
    float* o = x0 + (size_t)i * 6;
    const float* f = feats + (size_t)i * 3;
    const float* p = pos + (size_t)i * 3;
    o[0] = f[0]; o[1] = f[1]; o[2] = f[2];
    o[3] = p[0]; o[4] = p[1]; o[5] = p[2];
}

// ---------------------------------------------------------------- row norms
template <int D>
__global__ void norm2_kernel(const float* __restrict__ x, float* __restrict__ xn) {
    int i = blockIdx.x * 256 + threadIdx.x;
    if (i >= NPTS) return;
    const float* r = x + (size_t)i * D;
    float s = 0.f;
#pragma unroll
    for (int j = 0; j < D; ++j) s += r[j] * r[j];
    xn[i] = s;
}

// ---------------------------------------------------------------- hi/lo fp16 split (4 elems/thread)
__global__ void split16_kernel(const float* __restrict__ x, unsigned short* __restrict__ xh,
                               unsigned short* __restrict__ xl) {
    int i = blockIdx.x * 256 + threadIdx.x;   // over NPTS*64/4
    float4 v = ((const float4*)x)[i];
    float vv[4] = {v.x, v.y, v.z, v.w};
    short4v hh, ll;
#pragma unroll
    for (int j = 0; j < 4; ++j) {
        _Float16 hf = (_Float16)vv[j];
        hh[j] = __builtin_bit_cast(short, hf);
        _Float16 lf = (_Float16)(vv[j] - (float)hf);
        ll[j] = __builtin_bit_cast(short, lf);
    }
    ((short4v*)xh)[i] = hh;
    ((short4v*)xl)[i] = ll;
}

// ---------------------------------------------------------------- pairwise d2, fp32 VALU (D=6 layer)
template <int D>
__global__ void __launch_bounds__(256) dist_kernel(const float* __restrict__ x,
                                                   const float* __restrict__ xn,
                                                   float* __restrict__ d2, int b0) {
    int bz = blockIdx.z;
    int b  = b0 + bz;
    const float* xb  = x  + (size_t)b * PTS * D;
    const float* xnb = xn + (size_t)b * PTS;
    float* d2b = d2 + (size_t)bz * PTS * PTS;

    __shared__ float As[64][D + 1];
    __shared__ float Bs[64][D + 1];
    int row0 = blockIdx.y * 64;
    int col0 = blockIdx.x * 64;
    int tid = threadIdx.x;
    for (int i = tid; i < 64 * D; i += 256) {
        int r = i / D, c = i - r * D;
        As[r][c] = xb[(size_t)(row0 + r) * D + c];
        Bs[r][c] = xb[(size_t)(col0 + r) * D + c];
    }
    __syncthreads();
    int tx = tid & 15, ty = tid >> 4;
    float acc[4][4] = {};
    for (int k = 0; k < D; ++k) {
        float av[4], bv[4];
#pragma unroll
        for (int i = 0; i < 4; ++i) av[i] = As[ty * 4 + i][k];
#pragma unroll
        for (int j = 0; j < 4; ++j) bv[j] = Bs[tx * 4 + j][k];
#pragma unroll
        for (int i = 0; i < 4; ++i)
#pragma unroll
            for (int j = 0; j < 4; ++j) acc[i][j] += av[i] * bv[j];
    }
#pragma unroll
    for (int i = 0; i < 4; ++i) {
        int r = row0 + ty * 4 + i;
#pragma unroll
        for (int j = 0; j < 4; ++j) {
            int c = col0 + tx * 4 + j;
            d2b[(size_t)r * PTS + c] = xnb[c] - 2.f * acc[i][j];
        }
    }
}

// ---------------------------------------------------------------- pairwise d2 via MFMA hi/lo fp16 (D=64)
__global__ void __launch_bounds__(256) dist_mfma_kernel(
    const unsigned short* __restrict__ xh, const unsigned short* __restrict__ xl,
    const float* __restrict__ xn, float* __restrict__ d2, int b0)
{
    __shared__ char smem[128 * 256 + 64 * 256];   // 48KB: A(32K) | B(16K)
    __shared__ float sxn[64];
    char* sA = smem;
    char* sB = smem + 128 * 256;
    float* sS = (float*)smem;                     // reused after compute
    int bz = blockIdx.z, b = b0 + bz;
    int row0 = blockIdx.y * 128, col0 = blockIdx.x * 64;
    const unsigned short* xhb = xh + (size_t)b * PTS * 64;
    const unsigned short* xlb = xl + (size_t)b * PTS * 64;
    const float* xnb = xn + (size_t)b * PTS;
    float* d2b = d2 + (size_t)bz * PTS * PTS;
    int tid = threadIdx.x;

    for (int i = tid; i < 2048; i += 256) {
        int r = i >> 4, c = i & 15;
        const unsigned short* src = (c < 8) ? xhb + (size_t)(row0 + r) * 64 + (c << 3)
                                            : xlb + (size_t)(row0 + r) * 64 + ((c - 8) << 3);
        *(short8v*)(sA + ((r * 256 + (c << 4)) ^ ((r & 7) << 4))) = *(const short8v*)src;
    }
    for (int i = tid; i < 1024; i += 256) {
        int r = i >> 4, c = i & 15;
        const unsigned short* src = (c < 8) ? xhb + (size_t)(col0 + r) * 64 + (c << 3)
                                            : xlb + (size_t)(col0 + r) * 64 + ((c - 8) << 3);
        *(short8v*)(sB + ((r * 256 + (c << 4)) ^ ((r & 7) << 4))) = *(const short8v*)src;
    }
    if (tid < 64) sxn[tid] = xnb[col0 + tid];
    __syncthreads();

    int w = tid >> 6, l = tid & 63;
    int lr = l & 15, lg = l >> 4;

    half8v bh[4][2], bl[4][2];
#pragma unroll
    for (int n = 0; n < 4; ++n) {
        int c = n * 16 + lr, sw = (c & 7) << 4, base = c * 256;
#pragma unroll
        for (int ks = 0; ks < 2; ++ks) {
            bh[n][ks] = __builtin_bit_cast(half8v, *(short8v*)(sB + ((base + ks * 64 + lg * 16) ^ sw)));
            bl[n][ks] = __builtin_bit_cast(half8v, *(short8v*)(sB + ((base + 128 + ks * 64 + lg * 16) ^ sw)));
        }
    }

    f32x4 acc[2][4];
#pragma unroll
    for (int m = 0; m < 2; ++m)
#pragma unroll
        for (int n = 0; n < 4; ++n) acc[m][n] = (f32x4){0.f, 0.f, 0.f, 0.f};

#pragma unroll
    for (int m = 0; m < 2; ++m) {
        int r = w * 32 + m * 16 + lr, sw = (r & 7) << 4, base = r * 256;
        half8v ah0 = __builtin_bit_cast(half8v, *(short8v*)(sA + ((base + lg * 16) ^ sw)));
        half8v ah1 = __builtin_bit_cast(half8v, *(short8v*)(sA + ((base + 64 + lg * 16) ^ sw)));
        half8v al0 = __builtin_bit_cast(half8v, *(short8v*)(sA + ((base + 128 + lg * 16) ^ sw)));
        half8v al1 = __builtin_bit_cast(half8v, *(short8v*)(sA + ((base + 192 + lg * 16) ^ sw)));
#pragma unroll
        for (int n = 0; n < 4; ++n) {
            f32x4 a = acc[m][n];
            a = __builtin_amdgcn_mfma_f32_16x16x32_f16(ah0, bh[n][0], a, 0, 0, 0);
            a = __builtin_amdgcn_mfma_f32_16x16x32_f16(ah1, bh[n][1], a, 0, 0, 0);
            a = __builtin_amdgcn_mfma_f32_16x16x32_f16(al0, bh[n][0], a, 0, 0, 0);
            a = __builtin_amdgcn_mfma_f32_16x16x32_f16(al1, bh[n][1], a, 0, 0, 0);
            a = __builtin_amdgcn_mfma_f32_16x16x32_f16(ah0, bl[n][0], a, 0, 0, 0);
            a = __builtin_amdgcn_mfma_f32_16x16x32_f16(ah1, bl[n][1], a, 0, 0, 0);
            acc[m][n] = a;
        }
    }
    __syncthreads();   // all sA/sB reads complete; safe to reuse as sS

#pragma unroll
    for (int m = 0; m < 2; ++m)
#pragma unroll
        for (int n = 0; n < 4; ++n) {
            int rl = w * 32 + m * 16 + lg * 4;
            int col = n * 16 + lr;
#pragma unroll
            for (int j = 0; j < 4; ++j)
                sS[(rl + j) * 64 + col] = acc[m][n][j];
        }
    __syncthreads();

    for (int i = tid; i < 2048; i += 256) {
        int r = i >> 4, c4 = (i & 15) << 2;
        float4 v = *(float4*)&sS[r * 64 + c4];
        float4 o;
        o.x = sxn[c4 + 0] - 2.f * v.x;
        o.y = sxn[c4 + 1] - 2.f * v.y;
        o.z = sxn[c4 + 2] - 2.f * v.z;
        o.w = sxn[c4 + 3] - 2.f * v.w;
        *(float4*)&d2b[(size_t)(row0 + r) * PTS + col0 + c4] = o;
    }
}

// ---------------------------------------------------------------- top-K smallest, 1 wave/row, reg-resident
#define GMIN8(B, GV, GJ) do {                                         \
    GV = va[(B)];     GJ = (B);                                       \
    if (va[(B)+1] < GV) { GV = va[(B)+1]; GJ = (B)+1; }               \
    if (va[(B)+2] < GV) { GV = va[(B)+2]; GJ = (B)+2; }               \
    if (va[(B)+3] < GV) { GV = va[(B)+3]; GJ = (B)+3; }               \
    if (va[(B)+4] < GV) { GV = va[(B)+4]; GJ = (B)+4; }               \
    if (va[(B)+5] < GV) { GV = va[(B)+5]; GJ = (B)+5; }               \
    if (va[(B)+6] < GV) { GV = va[(B)+6]; GJ = (B)+6; }               \
    if (va[(B)+7] < GV) { GV = va[(B)+7]; GJ = (B)+7; }               \
} while (0)

#define INVAL8(B, GV, GJ, JS) do {                                    \
    va[(B)+0] = ((B)+0 == (JS)) ? INFV : va[(B)+0];                   \
    va[(B)+1] = ((B)+1 == (JS)) ? INFV : va[(B)+1];                   \
    va[(B)+2] = ((B)+2 == (JS)) ? INFV : va[(B)+2];                   \
    va[(B)+3] = ((B)+3 == (JS)) ? INFV : va[(B)+3];                   \
    va[(B)+4] = ((B)+4 == (JS)) ? INFV : va[(B)+4];                   \
    va[(B)+5] = ((B)+5 == (JS)) ? INFV : va[(B)+5];                   \
    va[(B)+6] = ((B)+6 == (JS)) ? INFV : va[(B)+6];                   \
    va[(B)+7] = ((B)+7 == (JS)) ? INFV : va[(B)+7];                   \
    GMIN8(B, GV, GJ);                                                 \
} while (0)

__global__ void __launch_bounds__(256) topk_kernel(const float* __restrict__ d2,
                                                   int* __restrict__ nbr, int b0) {
    const float INFV = __builtin_inff();
    int wid = threadIdx.x >> 6, lane = threadIdx.x & 63;
    int pl = blockIdx.x * 4 + wid;
    int bz = blockIdx.y;
    const float* row = d2 + ((size_t)bz * PTS + pl) * PTS;

    float va[32];
#pragma unroll
    for (int j8 = 0; j8 < 8; ++j8) {
        float4 v = *(const float4*)&row[j8 * 256 + lane * 4];
        va[j8 * 4 + 0] = v.x; va[j8 * 4 + 1] = v.y;
        va[j8 * 4 + 2] = v.z; va[j8 * 4 + 3] = v.w;
    }

    float g0v, g1v, g2v, g3v;
    int   g0j, g1j, g2j, g3j;
    GMIN8(0,  g0v, g0j);
    GMIN8(8,  g1v, g1j);
    GMIN8(16, g2v, g2j);
    GMIN8(24, g3v, g3j);

    int gbase = (b0 + bz) * PTS;
    int* outp = nbr + (size_t)(gbase + pl) * KNN;

    for (int k = 0; k < KNN; ++k) {
        float lv = g0v; int lj = g0j;
        if (g1v < lv) { lv = g1v; lj = g1j; }
        if (g2v < lv) { lv = g2v; lj = g2j; }
        if (g3v < lv) { lv = g3v; lj = g3j; }
        float wm = lv;
#pragma unroll
        for (int off = 1; off < 64; off <<= 1) wm = fminf(wm, __shfl_xor(wm, off));
        int mycol = (lv == wm) ? (((lj >> 2) << 8) | (lane << 2) | (lj & 3)) : 0x7fffffff;
        int wc = mycol;
#pragma unroll
        for (int off = 1; off < 64; off <<= 1) {
            int oc = __shfl_xor(wc, off);
            wc = oc < wc ? oc : wc;
        }
        if (lane == 0) outp[k] = gbase + wc;
        if (mycol == wc) {
            int js = lj;
            int gs = js >> 3;
            if (gs == 0)      INVAL8(0,  g0v, g0j, js);
            else if (gs == 1) INVAL8(8,  g1v, g1j, js);
            else if (gs == 2) INVAL8(16, g2v, g2j, js);
            else              INVAL8(24, g3v, g3j, js);
        }
    }
}

// ---------------------------------------------------------------- per-layer weight prep
__global__ void prep_kernel(const float* __restrict__ wa, const float* __restrict__ ba,
                            const float* __restrict__ wb,
                            float* __restrict__ wc, float* __restrict__ bc,
                            unsigned short* __restrict__ wbT, int D) {
    int t = blockIdx.x * 256 + threadIdx.x;
    if (t < D * 128) {
        int k = t >> 7, n = t & 127;
        wc[t] = (n < 64) ? (wa[k * 64 + n] - wa[(D + k) * 64 + n])
                         : wa[(D + k) * 64 + (n - 64)];
    }
    if (t < 128) bc[t] = (t < 64) ? ba[t] : 0.f;
    if (t < 4096) {
        int n = t >> 6, k = t & 63;
        wbT[t] = (unsigned short)f2h(wb[k * 64 + n]);
    }
}

// ---------------------------------------------------------------- head weight prep (transposed fp16)
__global__ void prep_head_kernel(const float* __restrict__ hw1, const float* __restrict__ hw2,
                                 const float* __restrict__ hw3,
                                 unsigned short* __restrict__ w1T, unsigned short* __restrict__ w2T,
                                 unsigned short* __restrict__ w3T) {
    int t = blockIdx.x * 256 + threadIdx.x;
    if (t < 192 * 1024) { int k = t / 1024, n = t - k * 1024; w1T[n * 192 + k] = (unsigned short)f2h(hw1[t]); }
    if (t < 1024 * 256) { int k = t >> 8, n = t & 255; w2T[n * 1024 + k] = (unsigned short)f2h(hw2[t]); }
    if (t < 256 * 128)  { int k = t >> 7, n = t & 127; w3T[n * 256 + k] = (unsigned short)f2h(hw3[t]); }
}

// ---------------------------------------------------------------- uv for layer 1 (D=6, compact x0)
__global__ void uv6_kernel(const float* __restrict__ x0, const float* __restrict__ wc,
                           const float* __restrict__ bc, float* __restrict__ uvout) {
    int t = blockIdx.x * 256 + threadIdx.x;
    int i = t >> 7, n = t & 127;
    const float* xr = x0 + (size_t)i * 6;
    float s = bc[n];
#pragma unroll
    for (int r = 0; r < 6; ++r) s += xr[r] * wc[r * 128 + n];
    uvout[t] = s;
}

// ---------------------------------------------------------------- EdgeConv via MFMA (fp16)
__global__ void __launch_bounds__(256) edge_mfma_kernel(
    const float* __restrict__ uv, const int* __restrict__ nbr,
    const unsigned short* __restrict__ wbT, const float* __restrict__ bb,
    float* __restrict__ xout, unsigned short* __restrict__ hcat16, int hoff)
{
    __shared__ short sA[256 * 64];   // 32 KB, swizzled
    __shared__ short sB[64 * 64];    // 8 KB, swizzled (holds wbT)
    __shared__ int snbr[8 * KNN];
    char* cA = (char*)sA;
    char* cB = (char*)sB;
    int tid = threadIdx.x;
    int p0 = blockIdx.x * 8;

    if (tid < 8 * KNN) snbr[tid] = nbr[(size_t)p0 * KNN + tid];
    for (int c = tid; c < 512; c += 256) {
        int n = c >> 3, k0 = (c & 7) << 3;
        short8v w = *(const short8v*)(wbT + n * 64 + k0);
        *(short8v*)(cB + ((n * 128 + (k0 << 1)) ^ ((n & 7) << 4))) = w;
    }
    __syncthreads();

    for (int t = tid; t < 1024; t += 256) {
        int r = t >> 2, c16 = (t & 3) << 4;
        int pl = r >> 5, e = r & 31;
        short h[16] __attribute__((aligned(16)));
        if (e < KNN) {
            int q = snbr[pl * KNN + e];
            const float4* up = (const float4*)(uv + (size_t)(p0 + pl) * 128 + c16);
            const float4* vp = (const float4*)(uv + (size_t)q * 128 + 64 + c16);
#pragma unroll
            for (int j = 0; j < 4; ++j) {
                float4 uu = up[j], vv = vp[j];
                h[j * 4 + 0] = f2h(fmaxf(uu.x + vv.x, 0.f));
                h[j * 4 + 1] = f2h(fmaxf(uu.y + vv.y, 0.f));
                h[j * 4 + 2] = f2h(fmaxf(uu.z + vv.z, 0.f));
                h[j * 4 + 3] = f2h(fmaxf(uu.w + vv.w, 0.f));
            }
        } else {
#pragma unroll
            for (int j = 0; j < 16; ++j) h[j] = 0;
        }
        int base = r * 128 + (c16 << 1);
        int s = (r & 7) << 4;
        *(short8v*)(cA + (base ^ s)) = *(short8v*)(h);
        *(short8v*)(cA + ((base + 16) ^ s)) = *(short8v*)(h + 8);
    }
    __syncthreads();

    int l = tid & 63, wvv2 = tid >> 6;
    int n0 = wvv2 << 4;
    int lr = l & 15, lg = l >> 4;
    int ncol = n0 + lr;
    int sb_s = (ncol & 7) << 4;
    half8v bf0 = __builtin_bit_cast(half8v, *(short8v*)(cB + ((ncol * 128 + lg * 16) ^ sb_s)));
    half8v bf1 = __builtin_bit_cast(half8v, *(short8v*)(cB + ((ncol * 128 + 64 + lg * 16) ^ sb_s)));
    float bias = bb[ncol];

#pragma unroll
    for (int pl = 0; pl < 8; ++pl) {
        int re = (pl << 5) + lr;
        int sa_s = (re & 7) << 4;
        int rbase = re * 128;
        half8v ae0 = __builtin_bit_cast(half8v, *(short8v*)(cA + ((rbase + lg * 16) ^ sa_s)));
        half8v ae1 = __builtin_bit_cast(half8v, *(short8v*)(cA + ((rbase + 64 + lg * 16) ^ sa_s)));
        half8v ao0 = __builtin_bit_cast(half8v, *(short8v*)(cA + ((rbase + 2048 + lg * 16) ^ sa_s)));
        half8v ao1 = __builtin_bit_cast(half8v, *(short8v*)(cA + ((rbase + 2048 + 64 + lg * 16) ^ sa_s)));
        f32x4 acce = {0.f, 0.f, 0.f, 0.f};
        f32x4 acco = {0.f, 0.f, 0.f, 0.f};
        acce = __builtin_amdgcn_mfma_f32_16x16x32_f16(ae0, bf0, acce, 0, 0, 0);
        acce = __builtin_amdgcn_mfma_f32_16x16x32_f16(ae1, bf1, acce, 0, 0, 0);
        acco = __builtin_amdgcn_mfma_f32_16x16x32_f16(ao0, bf0, acco, 0, 0, 0);
        acco = __builtin_amdgcn_mfma_f32_16x16x32_f16(ao1, bf1, acco, 0, 0, 0);
        float mv = fmaxf(fmaxf(acce[0], acce[1]), fmaxf(acce[2], acce[3]));
        if (lg == 0) {
            float mo = fmaxf(fmaxf(acco[0], acco[1]), fmaxf(acco[2], acco[3]));
            mv = fmaxf(mv, mo);
        }
        mv = fmaxf(mv, __shfl_xor(mv, 16));
        mv = fmaxf(mv, __shfl_xor(mv, 32));
        if (l < 16) {
            int gp = p0 + pl;
            float o = mv + bias;
            xout[(size_t)gp * 64 + ncol] = o;
            hcat16[(size_t)gp * 192 + hoff + ncol] = (unsigned short)f2h(o);
        }
    }
}

// ---------------------------------------------------------------- head GEMM via MFMA (fp16 in/out, fp32 acc)
// 128x64 C-tile, 4 waves x (2 M-frags x 4 N-frags), BK=64, XOR-swizzled LDS (round-11 best).
template <int RELU>
__global__ void __launch_bounds__(256) hgemm_kernel(
    const unsigned short* __restrict__ A, const unsigned short* __restrict__ wT,
    const float* __restrict__ bias, unsigned short* __restrict__ C,
    int M, int N, int K) {
    __shared__ char sA[128 * 128];
    __shared__ char sB[64 * 128];
    int tid = threadIdx.x;
    int row0 = blockIdx.y * 128, col0 = blockIdx.x * 64;
    int w = tid >> 6, l = tid & 63;
    int lr = l & 15, lg = l >> 4;

    f32x4 acc[2][4];
#pragma unroll
    for (int m = 0; m < 2; ++m)
#pragma unroll
        for (int n = 0; n < 4; ++n) acc[m][n] = (f32x4){0.f, 0.f, 0.f, 0.f};

    for (int kt = 0; kt < K; kt += 64) {
        for (int i = tid; i < 1024; i += 256) {
            int r = i >> 3, part = i & 7;
            short8v v = *(const short8v*)(A + (size_t)(row0 + r) * K + kt + part * 8);
            *(short8v*)(sA + ((r * 128 + part * 16) ^ ((r & 7) << 4))) = v;
        }
        for (int i = tid; i < 512; i += 256) {
            int r = i >> 3, part = i & 7;
            short8v v = *(const short8v*)(wT + (size_t)(col0 + r) * K + kt + part * 8);
            *(short8v*)(sB + ((r * 128 + part * 16) ^ ((r & 7) << 4))) = v;
        }
        __syncthreads();
#pragma unroll
        for (int ks = 0; ks < 2; ++ks) {
            half8v af0, af1, bf[4];
            {
                int r = w * 32 + lr;
                af0 = __builtin_bit_cast(half8v, *(short8v*)(sA + ((r * 128 + ks * 64 + lg * 16) ^ ((r & 7) << 4))));
                int r2 = r + 16;
                af1 = __builtin_bit_cast(half8v, *(short8v*)(sA + ((r2 * 128 + ks * 64 + lg * 16) ^ ((r2 & 7) << 4))));
            }
#pragma unroll
            for (int n = 0; n < 4; ++n) {
                int c = n * 16 + lr;
                bf[n] = __builtin_bit_cast(half8v, *(short8v*)(sB + ((c * 128 + ks * 64 + lg * 16) ^ ((c & 7) << 4))));
            }
#pragma unroll
            for (int n = 0; n < 4; ++n) {
                acc[0][n] = __builtin_amdgcn_mfma_f32_16x16x32_f16(af0, bf[n], acc[0][n], 0, 0, 0);
                acc[1][n] = __builtin_amdgcn_mfma_f32_16x16x32_f16(af1, bf[n], acc[1][n], 0, 0, 0);
            }
        }
        __syncthreads();
    }
#pragma unroll
    for (int m = 0; m < 2; ++m)
#pragma unroll
        for (int n = 0; n < 4; ++n) {
            int c = col0 + n * 16 + lr;
            float bj = bias[c];
#pragma unroll
            for (int j = 0; j < 4; ++j) {
                int r = row0 + w * 32 + m * 16 + lg * 4 + j;
                float v = acc[m][n][j] + bj;
                if (RELU) v = fmaxf(v, 0.f);
                C[(size_t)r * N + c] = (unsigned short)f2h(v);
            }
        }
}

// ---------------------------------------------------------------- generic fp32 GEMM + bias (uv only)
template <int RELU>
__global__ void __launch_bounds__(256) gemm_kernel(
    const float* __restrict__ A, const float* __restrict__ W,
    const float* __restrict__ bias, float* __restrict__ C,
    int M, int N, int Kd) {
    __shared__ float As[64][17];
    __shared__ float Bs[16][65];
    int row0 = blockIdx.y * 64, col0 = blockIdx.x * 64;
    int tid = threadIdx.x;
    int tx = tid & 15, ty = tid >> 4;
    float acc[4][4] = {};
    for (int kt = 0; kt < Kd; kt += 16) {
        for (int i = tid; i < 1024; i += 256) {
            int m = i >> 4, k = i & 15;
            As[m][k] = A[(size_t)(row0 + m) * Kd + kt + k];
        }
        for (int i = tid; i < 1024; i += 256) {
            int k = i >> 6, n = i & 63;
            Bs[k][n] = W[(size_t)(kt + k) * N + col0 + n];
        }
        __syncthreads();
#pragma unroll
        for (int k = 0; k < 16; ++k) {
            float av[4], bv[4];
#pragma unroll
            for (int i = 0; i < 4; ++i) av[i] = As[ty * 4 + i][k];
#pragma unroll
            for (int j = 0; j < 4; ++j) bv[j] = Bs[k][tx * 4 + j];
#pragma unroll
            for (int i = 0; i < 4; ++i)
#pragma unroll
                for (int j = 0; j < 4; ++j) acc[i][j] += av[i] * bv[j];
        }
        __syncthreads();
    }
#pragma unroll
    for (int j = 0; j < 4; ++j) {
        int c = col0 + tx * 4 + j;
        float bj = bias[c];
#pragma unroll
        for (int i = 0; i < 4; ++i) {
            int r = row0 + ty * 4 + i;
            float vv = acc[i][j] + bj;
            if (RELU) vv = fmaxf(vv, 0.f);
            C[(size_t)r * N + c] = vv;
        }
    }
}

// ---------------------------------------------------------------- final 128->13 + log_softmax (fp16 input)
__global__ void __launch_bounds__(256) final_kernel(const unsigned short* __restrict__ h3,
                                                    const float* __restrict__ w,
                                                    const float* __restrict__ bias,
                                                    float* __restrict__ out, int M) {
    __shared__ float sw[128 * 13];
    __shared__ float sb[13];
    int tid = threadIdx.x;
    for (int i = tid; i < 128 * 13; i += 256) sw[i] = w[i];
    if (tid < 13) sb[tid] = bias[tid];
    __syncthreads();
    int m = blockIdx.x * 256 + tid;
    if (m >= M) return;
    const short8v* hrow = (const short8v*)(h3 + (size_t)m * 128);
    float o[13];
#pragma unroll
    for (int c = 0; c < 13; ++c) o[c] = sb[c];
    for (int k8 = 0; k8 < 16; ++k8) {
        half8v hv = __builtin_bit_cast(half8v, hrow[k8]);
        int k = k8 * 8;
#pragma unroll
        for (int j = 0; j < 8; ++j) {
            float hf = h2f(hv[j]);
#pragma unroll
            for (int c = 0; c < 13; ++c) o[c] += hf * sw[(k + j) * 13 + c];
        }
    }
    float mx = o[0];
#pragma unroll
    for (int c = 1; c < 13; ++c) mx = fmaxf(mx, o[c]);
    float s = 0.f;
#pragma unroll
    for (int c = 0; c < 13; ++c) s += expf(o[c] - mx);
    float ls = logf(s);
    float* op = out + (size_t)m * 13;
#pragma unroll
    for (int c = 0; c < 13; ++c) op[c] = o[c] - mx - ls;
}

// ---------------------------------------------------------------- launch
extern "C" void kernel_launch(void* const* d_in, const int* in_sizes, int n_in,
                              void* d_out, int out_size, void* d_ws, size_t ws_size,
                              hipStream_t stream) {
    const float* feats = (const float*)d_in[0];
    const float* pos   = (const float*)d_in[1];
    const float* w1a = (const float*)d_in[3];
    const float* b1a = (const float*)d_in[4];
    const float* w1b = (const float*)d_in[5];
    const float* b1b = (const float*)d_in[6];
    const float* w2a = (const float*)d_in[7];
    const float* b2a = (const float*)d_in[8];
    const float* w2b = (const float*)d_in[9];
    const float* b2b = (const float*)d_in[10];
    const float* w3a = (const float*)d_in[11];
    const float* b3a = (const float*)d_in[12];
    const float* w3b = (const float*)d_in[13];
    const float* b3b = (const float*)d_in[14];
    const float* hw1 = (const float*)d_in[15];
    const float* hb1 = (const float*)d_in[16];
    const float* hw2 = (const float*)d_in[17];
    const float* hb2 = (const float*)d_in[18];
    const float* hw3 = (const float*)d_in[19];
    const float* hb3 = (const float*)d_in[20];
    const float* hw4 = (const float*)d_in[21];
    const float* hb4 = (const float*)d_in[22];
    float* out = (float*)d_out;
    char* ws = (char*)d_ws;

    constexpr size_t OFF_X0  = 0;                                        // NPTS*6*4
    constexpr size_t OFF_X1  = OFF_X0 + (size_t)NPTS * 6 * 4;
    constexpr size_t OFF_X2  = OFF_X1 + (size_t)NPTS * 64 * 4;
    constexpr size_t OFF_X3  = OFF_X2 + (size_t)NPTS * 64 * 4;
    constexpr size_t OFF_H16 = OFF_X3 + (size_t)NPTS * 64 * 4;
    constexpr size_t OFF_IDX = OFF_H16 + (size_t)NPTS * 192 * 2;
    constexpr size_t OFF_XN  = OFF_IDX + (size_t)NPTS * KNN * 4;
    constexpr size_t OFF_WC  = OFF_XN + (size_t)NPTS * 4;
    constexpr size_t OFF_BC  = OFF_WC + 64 * 128 * 4;
    constexpr size_t OFF_WBT = OFF_BC + 128 * 4;
    constexpr size_t OFF_W1T = OFF_WBT + 4096 * 2;
    constexpr size_t OFF_W2T = OFF_W1T + (size_t)1024 * 192 * 2;
    constexpr size_t OFF_W3T = OFF_W2T + (size_t)256 * 1024 * 2;
    constexpr size_t OFF_XH  = OFF_W3T + (size_t)128 * 256 * 2;
    constexpr size_t OFF_XL  = OFF_XH + (size_t)NPTS * 64 * 2;
    constexpr size_t OFF_BIG = OFF_XL + (size_t)NPTS * 64 * 2;

    float* x0   = (float*)(ws + OFF_X0);
    float* x1   = (float*)(ws + OFF_X1);
    float* x2b  = (float*)(ws + OFF_X2);
    float* x3   = (float*)(ws + OFF_X3);
    unsigned short* hcat16 = (unsigned short*)(ws + OFF_H16);
    int*   idxb = (int*)(ws + OFF_IDX);
    float* xn   = (float*)(ws + OFF_XN);
    float* wc   = (float*)(ws + OFF_WC);
    float* bc   = (float*)(ws + OFF_BC);
    unsigned short* wbT = (unsigned short*)(ws + OFF_WBT);
    unsigned short* w1T = (unsigned short*)(ws + OFF_W1T);
    unsigned short* w2T = (unsigned short*)(ws + OFF_W2T);
    unsigned short* w3T = (unsigned short*)(ws + OFF_W3T);
    unsigned short* xh  = (unsigned short*)(ws + OFF_XH);
    unsigned short* xl  = (unsigned short*)(ws + OFF_XL);
    float* big  = (float*)(ws + OFF_BIG);
    float* uvb  = big;   // uv shares big with d2/head (disjoint lifetimes)

    size_t avail = (ws_size > OFF_BIG) ? ws_size - OFF_BIG : 0;
    int NB = (int)(avail / ((size_t)PTS * PTS * 4));
    if (NB < 1) NB = 1;
    if (NB > 8) NB = 8;   // up to full-batch slab (128 MB, L3-resident): 1 dist+1 topk launch/layer

    build_x0_kernel<<<NPTS / 256, 256, 0, stream>>>(feats, pos, x0);
    prep_head_kernel<<<1024, 256, 0, stream>>>(hw1, hw2, hw3, w1T, w2T, w3T);

    // ---------------- layer 1 (D=6, fp32 dist) ----------------
    norm2_kernel<6><<<NPTS / 256, 256, 0, stream>>>(x0, xn);
    for (int b0 = 0; b0 < BATCH; b0 += NB) {
        int nb = BATCH - b0 < NB ? BATCH - b0 : NB;
        dist_kernel<6><<<dim3(PTS / 64, PTS / 64, nb), 256, 0, stream>>>(x0, xn, big, b0);
        topk_kernel<<<dim3(PTS / 4, nb), 256, 0, stream>>>(big, idxb, b0);
    }
    prep_kernel<<<32, 256, 0, stream>>>(w1a, b1a, w1b, wc, bc, wbT, 6);
    uv6_kernel<<<NPTS * 128 / 256, 256, 0, stream>>>(x0, wc, bc, uvb);
    edge_mfma_kernel<<<NPTS / 8, 256, 0, stream>>>(uvb, idxb, wbT, b1b, x1, hcat16, 0);

#define KNN64_PASS(XCUR)                                                                   \
    do {                                                                                   \
        norm2_kernel<64><<<NPTS / 256, 256, 0, stream>>>(XCUR, xn);                        \
        split16_kernel<<<NPTS * 64 / 4 / 256, 256, 0, stream>>>(XCUR, xh, xl);             \
        for (int b0 = 0; b0 < BATCH; b0 += NB) {                                           \
            int nb = BATCH - b0 < NB ? BATCH - b0 : NB;                                    \
            dist_mfma_kernel<<<dim3(PTS / 64, PTS / 128, nb), 256, 0, stream>>>(           \
                xh, xl, xn, big, b0);                                                      \
            topk_kernel<<<dim3(PTS / 4, nb), 256, 0, stream>>>(big, idxb, b0);             \
        }                                                                                  \
    } while (0)

    // ---------------- layer 2 (D=64) ----------------
    KNN64_PASS(x1);
    prep_kernel<<<32, 256, 0, stream>>>(w2a, b2a, w2b, wc, bc, wbT, 64);
    gemm_kernel<0><<<dim3(2, 256), 256, 0, stream>>>(x1, wc, bc, uvb, NPTS, 128, 64);
    edge_mfma_kernel<<<NPTS / 8, 256, 0, stream>>>(uvb, idxb, wbT, b2b, x2b, hcat16, 64);

    // ---------------- layer 3 (D=64) ----------------
    KNN64_PASS(x2b);
    prep_kernel<<<32, 256, 0, stream>>>(w3a, b3a, w3b, wc, bc, wbT, 64);
    gemm_kernel<0><<<dim3(2, 256), 256, 0, stream>>>(x2b, wc, bc, uvb, NPTS, 128, 64);
    edge_mfma_kernel<<<NPTS / 8, 256, 0, stream>>>(uvb, idxb, wbT, b3b, x3, hcat16, 128);

    // ---------------- head MLP (fp16 MFMA, 128x64 tiles) ----------------
    size_t need = (size_t)NPTS * (1024 + 256 + 128) * 2;
    int RCH = (avail >= need) ? NPTS : 2048;
    unsigned short* h1 = (unsigned short*)big;
    unsigned short* h2 = h1 + (size_t)RCH * 1024;
    unsigned short* h3 = h2 + (size_t)RCH * 256;
    for (int c0 = 0; c0 < NPTS; c0 += RCH) {
        const unsigned short* Ain = hcat16 + (size_t)c0 * 192;
        hgemm_kernel<1><<<dim3(1024 / 64, RCH / 128), 256, 0, stream>>>(Ain, w1T, hb1, h1, RCH, 1024, 192);
        hgemm_kernel<1><<<dim3(256 / 64, RCH / 128), 256, 0, stream>>>(h1, w2T, hb2, h2, RCH, 256, 1024);
        hgemm_kernel<1><<<dim3(128 / 64, RCH / 128), 256, 0, stream>>>(h2, w3T, hb3, h3, RCH, 128, 256);
        final_kernel<<<RCH / 256, 256, 0, stream>>>(h3, hw4, hb4, out + (size_t)c0 * 13, RCH);
    }
#undef KNN64_PASS
}